// Round 1
// baseline (212.921 us; speedup 1.0000x reference)
//
#include <hip/hip_runtime.h>

#define T_TOK 2048
#define AD    1024
#define HID   150
#define LW    10
#define NSTART (T_TOK - LW + 1)   // 2039
#define NSPAN  (NSTART * LW)      // 20390
#define RS    152                 // padded row stride (floats), 608B, 16B-aligned

// workspace offsets (in floats)
#define OFF_AH  0
#define OFF_SA  (OFF_AH + T_TOK*RS)
#define OFF_SB  (OFF_SA + T_TOK*RS)
#define OFF_EC  (OFF_SB + T_TOK*RS)
#define OFF_WT  (OFF_EC + T_TOK*RS)     // 16 rows reserved
#define OFF_ATT (OFF_WT + 16*RS)
#define OFF_H1  (OFF_ATT + T_TOK)

// ---------------------------------------------------------------------------
// k_main: per 8 tokens, compute
//   AH = relu(states @ attn_W1 + attn_b1)   cols   0..149  (thread j <150)
//   SA = states @ score_W1[0:1024]          cols 150..299
//   SB = states @ score_W1[1024:2048]       cols 300..449
// Thread j owns one output column for 8 tokens; A reads are wave-uniform
// (scalar-cache friendly), B reads coalesced across threads.
// ---------------------------------------------------------------------------
__global__ __launch_bounds__(512) void k_main(
    const float* __restrict__ states,
    const float* __restrict__ attn_W1, const float* __restrict__ attn_b1,
    const float* __restrict__ score_W1, float* __restrict__ ws) {
  const int t0 = blockIdx.x * 8;
  const int j  = threadIdx.x;
  const float* Bp; int jj; float* Cp; float bias = 0.f; bool act = false;
  if (j < HID)      { Bp = attn_W1;           jj = j;       Cp = ws + OFF_AH; act = true; bias = attn_b1[j]; }
  else if (j < 300) { Bp = score_W1;          jj = j - 150; Cp = ws + OFF_SA; }
  else if (j < 450) { Bp = score_W1 + AD*HID; jj = j - 300; Cp = ws + OFF_SB; }
  else return;

  const float4* A4 = reinterpret_cast<const float4*>(states) + (size_t)t0 * (AD/4);
  float acc[8];
#pragma unroll
  for (int t = 0; t < 8; ++t) acc[t] = 0.f;

  for (int c4 = 0; c4 < AD/4; ++c4) {
    const int cb = c4 * 4;
    const float w0 = Bp[(cb+0)*HID + jj];
    const float w1 = Bp[(cb+1)*HID + jj];
    const float w2 = Bp[(cb+2)*HID + jj];
    const float w3 = Bp[(cb+3)*HID + jj];
#pragma unroll
    for (int t = 0; t < 8; ++t) {
      float4 a = A4[t*(AD/4) + c4];
      acc[t] = fmaf(a.x, w0, acc[t]);
      acc[t] = fmaf(a.y, w1, acc[t]);
      acc[t] = fmaf(a.z, w2, acc[t]);
      acc[t] = fmaf(a.w, w3, acc[t]);
    }
  }
#pragma unroll
  for (int t = 0; t < 8; ++t) {
    float o = acc[t] + bias;
    if (act) o = fmaxf(o, 0.f);
    Cp[(size_t)(t0 + t)*RS + jj] = o;
  }
}

// ---------------------------------------------------------------------------
// k_ec: EC = embeds @ score_W1[2048:3072]   [2048,150]
// ---------------------------------------------------------------------------
__global__ __launch_bounds__(192) void k_ec(
    const float* __restrict__ embeds, const float* __restrict__ score_W1,
    float* __restrict__ ws) {
  const int t0 = blockIdx.x * 8;
  const int j  = threadIdx.x;
  if (j >= HID) return;
  const float* Bp = score_W1 + 2*AD*HID;
  float* Cp = ws + OFF_EC;

  const float4* A4 = reinterpret_cast<const float4*>(embeds) + (size_t)t0 * (AD/4);
  float acc[8];
#pragma unroll
  for (int t = 0; t < 8; ++t) acc[t] = 0.f;

  for (int c4 = 0; c4 < AD/4; ++c4) {
    const int cb = c4 * 4;
    const float w0 = Bp[(cb+0)*HID + j];
    const float w1 = Bp[(cb+1)*HID + j];
    const float w2 = Bp[(cb+2)*HID + j];
    const float w3 = Bp[(cb+3)*HID + j];
#pragma unroll
    for (int t = 0; t < 8; ++t) {
      float4 a = A4[t*(AD/4) + c4];
      acc[t] = fmaf(a.x, w0, acc[t]);
      acc[t] = fmaf(a.y, w1, acc[t]);
      acc[t] = fmaf(a.z, w2, acc[t]);
      acc[t] = fmaf(a.w, w3, acc[t]);
    }
  }
#pragma unroll
  for (int t = 0; t < 8; ++t)
    Cp[(size_t)(t0 + t)*RS + j] = acc[t];
}

// ---------------------------------------------------------------------------
// k_wt: WT[b] = width_table[b] @ score_W1[3072:3092] + score_b1   (9 rows)
// ---------------------------------------------------------------------------
__global__ void k_wt(const float* __restrict__ width_table,
                     const float* __restrict__ score_W1,
                     const float* __restrict__ score_b1,
                     float* __restrict__ ws) {
  const int j = threadIdx.x;
  if (j >= HID) return;
  float* WT = ws + OFF_WT;
  for (int b = 0; b < 9; ++b) {
    float acc = score_b1[j];
#pragma unroll
    for (int d = 0; d < 20; ++d)
      acc = fmaf(width_table[b*20 + d], score_W1[(3*AD + d)*HID + j], acc);
    WT[b*RS + j] = acc;
  }
}

// ---------------------------------------------------------------------------
// k_attn23: attn[t] = relu(AH[t] @ attn_W2 + b2) @ attn_W3 + b3  (8 tokens/blk)
// ---------------------------------------------------------------------------
__global__ __launch_bounds__(192) void k_attn23(
    const float* __restrict__ attn_W2, const float* __restrict__ attn_b2,
    const float* __restrict__ attn_W3, const float* __restrict__ attn_b3,
    float* __restrict__ ws) {
  const int t0 = blockIdx.x * 8;
  const int j  = threadIdx.x;
  __shared__ float red[8][RS];
  const float* AH = ws + OFF_AH;

  if (j < HID) {
    float acc[8];
#pragma unroll
    for (int t = 0; t < 8; ++t) acc[t] = 0.f;
    const float4* Hp = reinterpret_cast<const float4*>(AH) + (size_t)t0*(RS/4);
    for (int k4 = 0; k4 < 37; ++k4) {
      const int kb = k4*4;
      const float w0 = attn_W2[(kb+0)*HID + j];
      const float w1 = attn_W2[(kb+1)*HID + j];
      const float w2 = attn_W2[(kb+2)*HID + j];
      const float w3 = attn_W2[(kb+3)*HID + j];
#pragma unroll
      for (int t = 0; t < 8; ++t) {
        float4 h = Hp[t*(RS/4) + k4];
        acc[t] = fmaf(h.x, w0, acc[t]);
        acc[t] = fmaf(h.y, w1, acc[t]);
        acc[t] = fmaf(h.z, w2, acc[t]);
        acc[t] = fmaf(h.w, w3, acc[t]);
      }
    }
#pragma unroll
    for (int k = 148; k < HID; ++k) {
      const float w = attn_W2[k*HID + j];
#pragma unroll
      for (int t = 0; t < 8; ++t)
        acc[t] = fmaf(AH[(size_t)(t0+t)*RS + k], w, acc[t]);
    }
    const float b2 = attn_b2[j], w3v = attn_W3[j];
#pragma unroll
    for (int t = 0; t < 8; ++t)
      red[t][j] = fmaxf(acc[t] + b2, 0.f) * w3v;
  }
  __syncthreads();
  if (j < 8) {
    float s = attn_b3[0];
    for (int i = 0; i < HID; ++i) s += red[j][i];
    ws[OFF_ATT + t0 + j] = s;
  }
}

// ---------------------------------------------------------------------------
// k_h1: per start i1, all 10 widths:
//   prefix softmax over attn scores, h1 = SA[i1]+SB[i2]+prefix/D + WT[bin]+b1
//   (b1 already folded into WT). relu -> H1[n][k], n = i1*10 + (w-1)
// ---------------------------------------------------------------------------
__global__ __launch_bounds__(192) void k_h1(float* __restrict__ ws) {
  const int i1 = blockIdx.x;
  const int j  = threadIdx.x;
  const float* ATT = ws + OFF_ATT;

  float a[10];
#pragma unroll
  for (int l = 0; l < 10; ++l) a[l] = ATT[i1 + l];
  float M = a[0];
#pragma unroll
  for (int l = 1; l < 10; ++l) M = fmaxf(M, a[l]);
  float e[10], inv[10], D = 0.f;
#pragma unroll
  for (int l = 0; l < 10; ++l) {
    e[l] = expf(a[l] - M);
    D += e[l];
    inv[l] = 1.f / D;
  }
  if (j >= HID) return;

  const float* SA = ws + OFF_SA;
  const float* SB = ws + OFF_SB;
  const float* EC = ws + OFF_EC;
  const float* WT = ws + OFF_WT;
  float* H1 = ws + OFF_H1 + (size_t)i1 * 10 * RS;

  const float sa = SA[(size_t)i1*RS + j];
  float rs = 0.f;
  const int binrow[10] = {1,2,3,4,4,4,4,5,5,5};
#pragma unroll
  for (int l = 0; l < 10; ++l) {
    rs = fmaf(e[l], EC[(size_t)(i1+l)*RS + j], rs);
    float h = sa + SB[(size_t)(i1+l)*RS + j] + WT[binrow[l]*RS + j] + rs*inv[l];
    H1[l*RS + j] = fmaxf(h, 0.f);
  }
}

// ---------------------------------------------------------------------------
// k_h2: out[n] = relu(H1[n] @ score_W2 + b2) @ score_W3 + b3   (8 spans/blk)
// ---------------------------------------------------------------------------
__global__ __launch_bounds__(192) void k_h2(
    const float* __restrict__ score_W2, const float* __restrict__ score_b2,
    const float* __restrict__ score_W3, const float* __restrict__ score_b3,
    const float* __restrict__ ws, float* __restrict__ out) {
  const int n0 = blockIdx.x * 8;
  const int j  = threadIdx.x;
  __shared__ float red[8][RS];
  const float* H1 = ws + OFF_H1;

  if (j < HID) {
    float acc[8];
#pragma unroll
    for (int t = 0; t < 8; ++t) acc[t] = 0.f;
    const float4* Hp[8];
#pragma unroll
    for (int t = 0; t < 8; ++t) {
      int n = n0 + t; if (n > NSPAN-1) n = NSPAN-1;
      Hp[t] = reinterpret_cast<const float4*>(H1 + (size_t)n*RS);
    }
    for (int k4 = 0; k4 < 37; ++k4) {
      const int kb = k4*4;
      const float w0 = score_W2[(kb+0)*HID + j];
      const float w1 = score_W2[(kb+1)*HID + j];
      const float w2 = score_W2[(kb+2)*HID + j];
      const float w3 = score_W2[(kb+3)*HID + j];
#pragma unroll
      for (int t = 0; t < 8; ++t) {
        float4 h = Hp[t][k4];
        acc[t] = fmaf(h.x, w0, acc[t]);
        acc[t] = fmaf(h.y, w1, acc[t]);
        acc[t] = fmaf(h.z, w2, acc[t]);
        acc[t] = fmaf(h.w, w3, acc[t]);
      }
    }
#pragma unroll
    for (int k = 148; k < HID; ++k) {
      const float w = score_W2[k*HID + j];
#pragma unroll
      for (int t = 0; t < 8; ++t)
        acc[t] = fmaf(reinterpret_cast<const float*>(Hp[t])[k], w, acc[t]);
    }
    const float b2 = score_b2[j], w3v = score_W3[j];
#pragma unroll
    for (int t = 0; t < 8; ++t)
      red[t][j] = fmaxf(acc[t] + b2, 0.f) * w3v;
  }
  __syncthreads();
  if (j < 8) {
    const int n = n0 + j;
    if (n < NSPAN) {
      float s = score_b3[0];
      for (int i = 0; i < HID; ++i) s += red[j][i];
      out[n] = s;
    }
  }
}

extern "C" void kernel_launch(void* const* d_in, const int* in_sizes, int n_in,
                              void* d_out, int out_size, void* d_ws, size_t ws_size,
                              hipStream_t stream) {
  const float* states      = (const float*)d_in[0];
  const float* embeds      = (const float*)d_in[1];
  const float* attn_W1     = (const float*)d_in[2];
  const float* attn_b1     = (const float*)d_in[3];
  const float* attn_W2     = (const float*)d_in[4];
  const float* attn_b2     = (const float*)d_in[5];
  const float* attn_W3     = (const float*)d_in[6];
  const float* attn_b3     = (const float*)d_in[7];
  const float* width_table = (const float*)d_in[8];
  const float* score_W1    = (const float*)d_in[9];
  const float* score_b1    = (const float*)d_in[10];
  const float* score_W2    = (const float*)d_in[11];
  const float* score_b2    = (const float*)d_in[12];
  const float* score_W3    = (const float*)d_in[13];
  const float* score_b3    = (const float*)d_in[14];
  float* out = (float*)d_out;
  float* ws  = (float*)d_ws;

  k_main  <<<T_TOK/8, 512, 0, stream>>>(states, attn_W1, attn_b1, score_W1, ws);
  k_ec    <<<T_TOK/8, 192, 0, stream>>>(embeds, score_W1, ws);
  k_wt    <<<1,       192, 0, stream>>>(width_table, score_W1, score_b1, ws);
  k_attn23<<<T_TOK/8, 192, 0, stream>>>(attn_W2, attn_b2, attn_W3, attn_b3, ws);
  k_h1    <<<NSTART,  192, 0, stream>>>(ws);
  k_h2    <<<(NSPAN+7)/8, 192, 0, stream>>>(score_W2, score_b2, score_W3, score_b3, ws, out);
}

// Round 2
// 96.818 us; speedup vs baseline: 2.1992x; 2.1992x over previous
//
#include <hip/hip_runtime.h>

#define T_TOK 2048
#define AD    1024
#define HID   150
#define LW    10
#define NSTART (T_TOK - LW + 1)   // 2039
#define NSPAN  (NSTART * LW)      // 20390
#define RS    152                 // padded row stride (floats), 608B, 16B-aligned

// workspace offsets (in floats)
#define OFF_AH  0
#define OFF_SA  (OFF_AH + T_TOK*RS)
#define OFF_SB  (OFF_SA + T_TOK*RS)
#define OFF_EC  (OFF_SB + T_TOK*RS)
#define OFF_WT  (OFF_EC + T_TOK*RS)     // 16 rows reserved
#define OFF_ATT (OFF_WT + 16*RS)
#define OFF_H1  (OFF_ATT + T_TOK)
// bf16 scratch lives INSIDE the H1 region (dead until k_h1 runs, which is
// after k_gemm): states_b | embeds_b | Wt  = 2.42M float-slots < 3.10M H1 slots
#define SB_SHORTS (T_TOK*AD)            // 2,097,152
#define WT_SHORTS (640*AD)

typedef __attribute__((ext_vector_type(8))) short bf16x8;
typedef __attribute__((ext_vector_type(4))) float f32x4;

__device__ inline unsigned short f2bf(float f) {
  unsigned u = __builtin_bit_cast(unsigned, f);
  u += 0x7fff + ((u >> 16) & 1);        // RNE
  return (unsigned short)(u >> 16);
}

__device__ inline void gld16(const void* g, void* l) {
  __builtin_amdgcn_global_load_lds(
      (const __attribute__((address_space(1))) unsigned int*)g,
      (__attribute__((address_space(3))) unsigned int*)l, 16, 0, 0);
}

// ---------------------------------------------------------------------------
// k_cvt: states+embeds fp32 -> bf16, 8 elems/thread
// ---------------------------------------------------------------------------
__global__ __launch_bounds__(256) void k_cvt(const float* __restrict__ st,
    const float* __restrict__ em, unsigned short* __restrict__ ob) {
  int i = blockIdx.x * 256 + threadIdx.x;       // 0..524287
  const float* src; unsigned short* dst; int idx;
  if (i < SB_SHORTS/8) { src = st; idx = i; dst = ob; }
  else { src = em; idx = i - SB_SHORTS/8; dst = ob + SB_SHORTS; }
  float4 a = ((const float4*)src)[idx*2];
  float4 b = ((const float4*)src)[idx*2+1];
  uint4 o;
  o.x = (unsigned)f2bf(a.x) | ((unsigned)f2bf(a.y) << 16);
  o.y = (unsigned)f2bf(a.z) | ((unsigned)f2bf(a.w) << 16);
  o.z = (unsigned)f2bf(b.x) | ((unsigned)f2bf(b.y) << 16);
  o.w = (unsigned)f2bf(b.z) | ((unsigned)f2bf(b.w) << 16);
  *(uint4*)(dst + (size_t)idx*8) = o;
}

// ---------------------------------------------------------------------------
// k_packw: Wt[n][k] bf16, n in 4 groups of 160 (150 used + 10 zero pad)
//   grp0: attn_W1 ; grp1..3: score_W1 rows [0,1024),[1024,2048),[2048,3072)
// ---------------------------------------------------------------------------
__global__ __launch_bounds__(256) void k_packw(const float* __restrict__ aw1,
    const float* __restrict__ sw1, unsigned short* __restrict__ Wt) {
  int n = blockIdx.x;                 // 0..639
  int t = threadIdx.x;                // k0 = t*4
  int grp = n / 160, j = n - grp*160;
  const float* src = (grp == 0) ? (aw1 + j) : (sw1 + (size_t)(grp-1)*AD*HID + j);
  bool ok = (j < HID);
  int k0 = t * 4;
  unsigned short v0 = ok ? f2bf(src[(size_t)(k0+0)*HID]) : 0;
  unsigned short v1 = ok ? f2bf(src[(size_t)(k0+1)*HID]) : 0;
  unsigned short v2 = ok ? f2bf(src[(size_t)(k0+2)*HID]) : 0;
  unsigned short v3 = ok ? f2bf(src[(size_t)(k0+3)*HID]) : 0;
  uint2 w; w.x = (unsigned)v0 | ((unsigned)v1 << 16);
  w.y = (unsigned)v2 | ((unsigned)v3 << 16);
  *(uint2*)(Wt + (size_t)n*AD + k0) = w;
}

// ---------------------------------------------------------------------------
// k_gemm: bf16 MFMA, swapped operands: D[n,m] = W^T-chunk @ A^T-chunk
//   grid.x = 64 row tiles (BM=32 tokens), grid.y = 8 (stream s=y>>1, half=y&1)
//   block = 320 thr (5 waves), wave w owns 16 output cols.
//   LDS: A [32][64] bf16, B [80][64] bf16, double buffered, chunk-XOR swizzle.
// ---------------------------------------------------------------------------
#define BM 32
#define KS 64
__global__ __launch_bounds__(320) void k_gemm(
    const unsigned short* __restrict__ Sb, const unsigned short* __restrict__ Eb,
    const unsigned short* __restrict__ Wt, const float* __restrict__ attn_b1,
    float* __restrict__ ws) {
  const int m0   = blockIdx.x * BM;
  const int s    = blockIdx.y >> 1;
  const int half = blockIdx.y & 1;
  const int tid  = threadIdx.x;
  const int lane = tid & 63, wv = tid >> 6;

  __shared__ unsigned short lA[2][BM*KS];   // 2 x 4KB
  __shared__ unsigned short lB[2][80*KS];   // 2 x 10KB

  const unsigned short* Ag = (s < 3 ? Sb : Eb) + (size_t)m0 * AD;
  const unsigned short* Bg = Wt + (size_t)(s*160 + half*80) * AD;

  f32x4 acc0 = {0.f,0.f,0.f,0.f}, acc1 = {0.f,0.f,0.f,0.f};

  // 14 segs of 64x16B: segs 0..9 = B (8 rows each), 10..13 = A (8 rows each)
  auto stage = [&](int kb, int buf) {
    for (int seg = wv; seg < 14; seg += 5) {
      if (seg < 10) {
        int c = seg*64 + lane;
        int row = c >> 3, ch = c & 7;
        gld16(Bg + (size_t)row*AD + kb + ((ch ^ (row & 7)) << 3),
              &lB[buf][seg*512]);
      } else {
        int c = (seg-10)*64 + lane;
        int row = c >> 3, ch = c & 7;
        gld16(Ag + (size_t)row*AD + kb + ((ch ^ (row & 7)) << 3),
              &lA[buf][(seg-10)*512]);
      }
    }
  };

  stage(0, 0);
  int buf = 0;
  const int r = lane & 15, g = lane >> 4;
  const int rx = wv*16 + r;         // X (weight) row in lB
  const int sw = r & 7;             // swizzle bits (same for rx, r, r+16)

  for (int kk = 0; kk < 16; ++kk) {
    __syncthreads();
    if (kk < 15) stage((kk+1)*KS, buf ^ 1);
#pragma unroll
    for (int z = 0; z < 2; ++z) {
      const int cz = z*4 + g;
      bf16x8 X  = *(const bf16x8*)&lB[buf][rx*KS      + ((cz ^ sw) << 3)];
      bf16x8 Y0 = *(const bf16x8*)&lA[buf][r*KS       + ((cz ^ sw) << 3)];
      bf16x8 Y1 = *(const bf16x8*)&lA[buf][(16+r)*KS  + ((cz ^ sw) << 3)];
      acc0 = __builtin_amdgcn_mfma_f32_16x16x32_bf16(X, Y0, acc0, 0, 0, 0);
      acc1 = __builtin_amdgcn_mfma_f32_16x16x32_bf16(X, Y1, acc1, 0, 0, 0);
    }
    buf ^= 1;
  }

  // epilogue: lane holds D[n = jn+q, m = m0 + f*16 + r]
  const int jn = half*80 + wv*16 + g*4;
  float* Cp = ws + (s==0 ? OFF_AH : s==1 ? OFF_SA : s==2 ? OFF_SB : OFF_EC);
#pragma unroll
  for (int f = 0; f < 2; ++f) {
    int m = m0 + f*16 + r;
    f32x4 a = f ? acc1 : acc0;
    if (s == 0) {
#pragma unroll
      for (int q = 0; q < 4; ++q)
        if (jn + q < HID) a[q] = fmaxf(a[q] + attn_b1[jn+q], 0.f);
    }
    float* d = Cp + (size_t)m*RS + jn;
    if (jn + 3 < HID) *(f32x4*)d = a;
    else {
#pragma unroll
      for (int q = 0; q < 4; ++q) if (jn + q < HID) d[q] = a[q];
    }
  }
}

// ---------------------------------------------------------------------------
// k_wt: WT[b] = width_table[b] @ score_W1[3072:3092] + score_b1   (9 rows)
// ---------------------------------------------------------------------------
__global__ void k_wt(const float* __restrict__ width_table,
                     const float* __restrict__ score_W1,
                     const float* __restrict__ score_b1,
                     float* __restrict__ ws) {
  const int j = threadIdx.x;
  if (j >= HID) return;
  float* WT = ws + OFF_WT;
  for (int b = 0; b < 9; ++b) {
    float acc = score_b1[j];
#pragma unroll
    for (int d = 0; d < 20; ++d)
      acc = fmaf(width_table[b*20 + d], score_W1[(3*AD + d)*HID + j], acc);
    WT[b*RS + j] = acc;
  }
}

// ---------------------------------------------------------------------------
// k_attn23: attn[t] = relu(AH[t] @ attn_W2 + b2) @ attn_W3 + b3  (8 tokens/blk)
// ---------------------------------------------------------------------------
__global__ __launch_bounds__(192) void k_attn23(
    const float* __restrict__ attn_W2, const float* __restrict__ attn_b2,
    const float* __restrict__ attn_W3, const float* __restrict__ attn_b3,
    float* __restrict__ ws) {
  const int t0 = blockIdx.x * 8;
  const int j  = threadIdx.x;
  __shared__ float red[8][RS];
  const float* AH = ws + OFF_AH;

  if (j < HID) {
    float acc[8];
#pragma unroll
    for (int t = 0; t < 8; ++t) acc[t] = 0.f;
    const float4* Hp = reinterpret_cast<const float4*>(AH) + (size_t)t0*(RS/4);
    for (int k4 = 0; k4 < 37; ++k4) {
      const int kb = k4*4;
      const float w0 = attn_W2[(kb+0)*HID + j];
      const float w1 = attn_W2[(kb+1)*HID + j];
      const float w2 = attn_W2[(kb+2)*HID + j];
      const float w3 = attn_W2[(kb+3)*HID + j];
#pragma unroll
      for (int t = 0; t < 8; ++t) {
        float4 h = Hp[t*(RS/4) + k4];
        acc[t] = fmaf(h.x, w0, acc[t]);
        acc[t] = fmaf(h.y, w1, acc[t]);
        acc[t] = fmaf(h.z, w2, acc[t]);
        acc[t] = fmaf(h.w, w3, acc[t]);
      }
    }
#pragma unroll
    for (int k = 148; k < HID; ++k) {
      const float w = attn_W2[k*HID + j];
#pragma unroll
      for (int t = 0; t < 8; ++t)
        acc[t] = fmaf(AH[(size_t)(t0+t)*RS + k], w, acc[t]);
    }
    const float b2 = attn_b2[j], w3v = attn_W3[j];
#pragma unroll
    for (int t = 0; t < 8; ++t)
      red[t][j] = fmaxf(acc[t] + b2, 0.f) * w3v;
  }
  __syncthreads();
  if (j < 8) {
    float s = attn_b3[0];
    for (int i = 0; i < HID; ++i) s += red[j][i];
    ws[OFF_ATT + t0 + j] = s;
  }
}

// ---------------------------------------------------------------------------
// k_h1: prefix softmax + gather-sum -> H1 (relu'd layer-1 activations)
// ---------------------------------------------------------------------------
__global__ __launch_bounds__(192) void k_h1(float* __restrict__ ws) {
  const int i1 = blockIdx.x;
  const int j  = threadIdx.x;
  const float* ATT = ws + OFF_ATT;

  float a[10];
#pragma unroll
  for (int l = 0; l < 10; ++l) a[l] = ATT[i1 + l];
  float M = a[0];
#pragma unroll
  for (int l = 1; l < 10; ++l) M = fmaxf(M, a[l]);
  float e[10], inv[10], D = 0.f;
#pragma unroll
  for (int l = 0; l < 10; ++l) {
    e[l] = expf(a[l] - M);
    D += e[l];
    inv[l] = 1.f / D;
  }
  if (j >= HID) return;

  const float* SA = ws + OFF_SA;
  const float* SB = ws + OFF_SB;
  const float* EC = ws + OFF_EC;
  const float* WT = ws + OFF_WT;
  float* H1 = ws + OFF_H1 + (size_t)i1 * 10 * RS;

  const float sa = SA[(size_t)i1*RS + j];
  float rs = 0.f;
  const int binrow[10] = {1,2,3,4,4,4,4,5,5,5};
#pragma unroll
  for (int l = 0; l < 10; ++l) {
    rs = fmaf(e[l], EC[(size_t)(i1+l)*RS + j], rs);
    float h = sa + SB[(size_t)(i1+l)*RS + j] + WT[binrow[l]*RS + j] + rs*inv[l];
    H1[l*RS + j] = fmaxf(h, 0.f);
  }
}

// ---------------------------------------------------------------------------
// k_h2: out[n] = relu(H1[n] @ score_W2 + b2) @ score_W3 + b3   (8 spans/blk)
// ---------------------------------------------------------------------------
__global__ __launch_bounds__(192) void k_h2(
    const float* __restrict__ score_W2, const float* __restrict__ score_b2,
    const float* __restrict__ score_W3, const float* __restrict__ score_b3,
    const float* __restrict__ ws, float* __restrict__ out) {
  const int n0 = blockIdx.x * 8;
  const int j  = threadIdx.x;
  __shared__ float red[8][RS];
  const float* H1 = ws + OFF_H1;

  if (j < HID) {
    float acc[8];
#pragma unroll
    for (int t = 0; t < 8; ++t) acc[t] = 0.f;
    const float4* Hp[8];
#pragma unroll
    for (int t = 0; t < 8; ++t) {
      int n = n0 + t; if (n > NSPAN-1) n = NSPAN-1;
      Hp[t] = reinterpret_cast<const float4*>(H1 + (size_t)n*RS);
    }
    for (int k4 = 0; k4 < 37; ++k4) {
      const int kb = k4*4;
      const float w0 = score_W2[(kb+0)*HID + j];
      const float w1 = score_W2[(kb+1)*HID + j];
      const float w2 = score_W2[(kb+2)*HID + j];
      const float w3 = score_W2[(kb+3)*HID + j];
#pragma unroll
      for (int t = 0; t < 8; ++t) {
        float4 h = Hp[t][k4];
        acc[t] = fmaf(h.x, w0, acc[t]);
        acc[t] = fmaf(h.y, w1, acc[t]);
        acc[t] = fmaf(h.z, w2, acc[t]);
        acc[t] = fmaf(h.w, w3, acc[t]);
      }
    }
#pragma unroll
    for (int k = 148; k < HID; ++k) {
      const float w = score_W2[k*HID + j];
#pragma unroll
      for (int t = 0; t < 8; ++t)
        acc[t] = fmaf(reinterpret_cast<const float*>(Hp[t])[k], w, acc[t]);
    }
    const float b2 = score_b2[j], w3v = score_W3[j];
#pragma unroll
    for (int t = 0; t < 8; ++t)
      red[t][j] = fmaxf(acc[t] + b2, 0.f) * w3v;
  }
  __syncthreads();
  if (j < 8) {
    const int n = n0 + j;
    if (n < NSPAN) {
      float s = score_b3[0];
      for (int i = 0; i < HID; ++i) s += red[j][i];
      out[n] = s;
    }
  }
}

extern "C" void kernel_launch(void* const* d_in, const int* in_sizes, int n_in,
                              void* d_out, int out_size, void* d_ws, size_t ws_size,
                              hipStream_t stream) {
  const float* states      = (const float*)d_in[0];
  const float* embeds      = (const float*)d_in[1];
  const float* attn_W1     = (const float*)d_in[2];
  const float* attn_b1     = (const float*)d_in[3];
  const float* attn_W2     = (const float*)d_in[4];
  const float* attn_b2     = (const float*)d_in[5];
  const float* attn_W3     = (const float*)d_in[6];
  const float* attn_b3     = (const float*)d_in[7];
  const float* width_table = (const float*)d_in[8];
  const float* score_W1    = (const float*)d_in[9];
  const float* score_b1    = (const float*)d_in[10];
  const float* score_W2    = (const float*)d_in[11];
  const float* score_b2    = (const float*)d_in[12];
  const float* score_W3    = (const float*)d_in[13];
  const float* score_b3    = (const float*)d_in[14];
  float* out = (float*)d_out;
  float* ws  = (float*)d_ws;

  unsigned short* Sb = (unsigned short*)(ws + OFF_H1);
  unsigned short* Eb = Sb + SB_SHORTS;
  unsigned short* Wt = Eb + SB_SHORTS;

  k_cvt   <<<2048, 256, 0, stream>>>(states, embeds, Sb);
  k_packw <<<640,  256, 0, stream>>>(attn_W1, score_W1, Wt);
  k_wt    <<<1,    192, 0, stream>>>(width_table, score_W1, score_b1, ws);
  k_gemm  <<<dim3(T_TOK/BM, 8), 320, 0, stream>>>(Sb, Eb, Wt, attn_b1, ws);
  k_attn23<<<T_TOK/8, 192, 0, stream>>>(attn_W2, attn_b2, attn_W3, attn_b3, ws);
  k_h1    <<<NSTART,  192, 0, stream>>>(ws);
  k_h2    <<<(NSPAN+7)/8, 192, 0, stream>>>(score_W2, score_b2, score_W3, score_b3, ws, out);
}

// Round 3
// 71.361 us; speedup vs baseline: 2.9837x; 1.3567x over previous
//
#include <hip/hip_runtime.h>

#define T_TOK 2048
#define AD    1024
#define HID   150
#define LW    10
#define NSTART (T_TOK - LW + 1)   // 2039
#define NSPAN  (NSTART * LW)      // 20390
#define RS    152                 // padded fp32 row stride

// workspace offsets (in floats)
#define OFF_AH  0
#define OFF_SA  (OFF_AH + T_TOK*RS)
#define OFF_SB  (OFF_SA + T_TOK*RS)
#define OFF_EC  (OFF_SB + T_TOK*RS)
#define OFF_WT  (OFF_EC + T_TOK*RS)     // 16 rows reserved
#define OFF_ATT (OFF_WT + 16*RS)
#define OFF_BF16 (OFF_ATT + T_TOK)
#define SB_SHORTS (T_TOK*AD)            // 2,097,152

typedef __attribute__((ext_vector_type(8))) short bf16x8;
typedef __attribute__((ext_vector_type(4))) float f32x4;

__device__ inline unsigned short f2bf(float f) {
  unsigned u = __builtin_bit_cast(unsigned, f);
  u += 0x7fff + ((u >> 16) & 1);        // RNE
  return (unsigned short)(u >> 16);
}

__device__ inline void gld16(const void* g, void* l) {
  __builtin_amdgcn_global_load_lds(
      (const __attribute__((address_space(1))) unsigned int*)g,
      (__attribute__((address_space(3))) unsigned int*)l, 16, 0, 0);
}

// ---------------------------------------------------------------------------
// k_cvt: states+embeds fp32 -> bf16
// ---------------------------------------------------------------------------
__global__ __launch_bounds__(256) void k_cvt(const float* __restrict__ st,
    const float* __restrict__ em, unsigned short* __restrict__ ob) {
  int i = blockIdx.x * 256 + threadIdx.x;       // 0..524287
  const float* src; unsigned short* dst; int idx;
  if (i < SB_SHORTS/8) { src = st; idx = i; dst = ob; }
  else { src = em; idx = i - SB_SHORTS/8; dst = ob + SB_SHORTS; }
  float4 a = ((const float4*)src)[idx*2];
  float4 b = ((const float4*)src)[idx*2+1];
  uint4 o;
  o.x = (unsigned)f2bf(a.x) | ((unsigned)f2bf(a.y) << 16);
  o.y = (unsigned)f2bf(a.z) | ((unsigned)f2bf(a.w) << 16);
  o.z = (unsigned)f2bf(b.x) | ((unsigned)f2bf(b.y) << 16);
  o.w = (unsigned)f2bf(b.z) | ((unsigned)f2bf(b.w) << 16);
  *(uint4*)(dst + (size_t)idx*8) = o;
}

// ---------------------------------------------------------------------------
// k_packw: Wt[n][k] bf16 via LDS tile transpose.
//   grp = blk>>3 (0:attn_W1, 1..3: score_W1 1024-row slices), kt = blk&7.
//   Coalesced fp32 reads, 16B-aligned bf16 writes.
// ---------------------------------------------------------------------------
__global__ __launch_bounds__(256) void k_packw(const float* __restrict__ aw1,
    const float* __restrict__ sw1, unsigned short* __restrict__ Wt) {
  __shared__ unsigned short T[152*136];   // row j, col kl (stride 136: 272B, 16B-mult)
  const int b = blockIdx.x, grp = b >> 3, kt = b & 7, t = threadIdx.x;
  const float* src = (grp == 0) ? aw1 : sw1 + (size_t)(grp-1)*AD*HID;
  const int k0 = kt * 128;
  for (int idx = t; idx < 128*152; idx += 256) {
    int kl = idx / 152, j = idx - kl*152;
    float v = (j < HID) ? src[(size_t)(k0+kl)*HID + j] : 0.f;
    T[j*136 + kl] = f2bf(v);
  }
  __syncthreads();
  for (int u = t; u < 160*16; u += 256) {
    int jj = u >> 4, kc = u & 15;
    bf16x8 v;
    if (jj < 152) v = *(const bf16x8*)&T[jj*136 + kc*8];
    else          v = (bf16x8){0,0,0,0,0,0,0,0};
    *(bf16x8*)&Wt[(size_t)(grp*160 + jj)*AD + k0 + kc*8] = v;
  }
}

// ---------------------------------------------------------------------------
// k_packw2: W2t[j][k] = W2[k][j] (bf16, [160][160] zero-pad), both MLPs
// ---------------------------------------------------------------------------
__global__ __launch_bounds__(256) void k_packw2(const float* __restrict__ sw2,
    const float* __restrict__ aw2, unsigned short* __restrict__ W2t,
    unsigned short* __restrict__ AW2t) {
  int idx = blockIdx.x * 256 + threadIdx.x;   // 0..51199
  const float* src; unsigned short* dst; int u;
  if (idx < 25600) { src = sw2; dst = W2t; u = idx; }
  else             { src = aw2; dst = AW2t; u = idx - 25600; }
  int j = u / 160, k = u - j*160;
  float v = (j < HID && k < HID) ? src[(size_t)k*HID + j] : 0.f;
  dst[u] = f2bf(v);
}

// ---------------------------------------------------------------------------
// k_gemm: layer-1 bf16 MFMA (AH/SA/SB/EC), unchanged from R1
// ---------------------------------------------------------------------------
#define BM 32
#define KS 64
__global__ __launch_bounds__(320) void k_gemm(
    const unsigned short* __restrict__ Sb, const unsigned short* __restrict__ Eb,
    const unsigned short* __restrict__ Wt, const float* __restrict__ attn_b1,
    float* __restrict__ ws) {
  const int m0   = blockIdx.x * BM;
  const int s    = blockIdx.y >> 1;
  const int half = blockIdx.y & 1;
  const int tid  = threadIdx.x;
  const int lane = tid & 63, wv = tid >> 6;

  __shared__ unsigned short lA[2][BM*KS];
  __shared__ unsigned short lB[2][80*KS];

  const unsigned short* Ag = (s < 3 ? Sb : Eb) + (size_t)m0 * AD;
  const unsigned short* Bg = Wt + (size_t)(s*160 + half*80) * AD;

  f32x4 acc0 = {0.f,0.f,0.f,0.f}, acc1 = {0.f,0.f,0.f,0.f};

  auto stage = [&](int kb, int buf) {
    for (int seg = wv; seg < 14; seg += 5) {
      if (seg < 10) {
        int c = seg*64 + lane;
        int row = c >> 3, ch = c & 7;
        gld16(Bg + (size_t)row*AD + kb + ((ch ^ (row & 7)) << 3), &lB[buf][seg*512]);
      } else {
        int c = (seg-10)*64 + lane;
        int row = c >> 3, ch = c & 7;
        gld16(Ag + (size_t)row*AD + kb + ((ch ^ (row & 7)) << 3), &lA[buf][(seg-10)*512]);
      }
    }
  };

  stage(0, 0);
  int buf = 0;
  const int r = lane & 15, g = lane >> 4;
  const int rx = wv*16 + r;
  const int sw = r & 7;

  for (int kk = 0; kk < 16; ++kk) {
    __syncthreads();
    if (kk < 15) stage((kk+1)*KS, buf ^ 1);
#pragma unroll
    for (int z = 0; z < 2; ++z) {
      const int cz = z*4 + g;
      bf16x8 X  = *(const bf16x8*)&lB[buf][rx*KS      + ((cz ^ sw) << 3)];
      bf16x8 Y0 = *(const bf16x8*)&lA[buf][r*KS       + ((cz ^ sw) << 3)];
      bf16x8 Y1 = *(const bf16x8*)&lA[buf][(16+r)*KS  + ((cz ^ sw) << 3)];
      acc0 = __builtin_amdgcn_mfma_f32_16x16x32_bf16(X, Y0, acc0, 0, 0, 0);
      acc1 = __builtin_amdgcn_mfma_f32_16x16x32_bf16(X, Y1, acc1, 0, 0, 0);
    }
    buf ^= 1;
  }

  const int jn = half*80 + wv*16 + g*4;
  float* Cp = ws + (s==0 ? OFF_AH : s==1 ? OFF_SA : s==2 ? OFF_SB : OFF_EC);
#pragma unroll
  for (int f = 0; f < 2; ++f) {
    int m = m0 + f*16 + r;
    f32x4 a = f ? acc1 : acc0;
    if (s == 0) {
#pragma unroll
      for (int q = 0; q < 4; ++q)
        if (jn + q < HID) a[q] = fmaxf(a[q] + attn_b1[jn+q], 0.f);
    }
    float* d = Cp + (size_t)m*RS + jn;
    if (jn + 3 < HID) *(f32x4*)d = a;
    else {
#pragma unroll
      for (int q = 0; q < 4; ++q) if (jn + q < HID) d[q] = a[q];
    }
  }
}

// ---------------------------------------------------------------------------
// k_wt: WT[b] = width_table[b] @ score_W1[3072:3092] + score_b1
// ---------------------------------------------------------------------------
__global__ void k_wt(const float* __restrict__ width_table,
                     const float* __restrict__ score_W1,
                     const float* __restrict__ score_b1,
                     float* __restrict__ ws) {
  const int j = threadIdx.x;
  if (j >= HID) return;
  float* WT = ws + OFF_WT;
  for (int b = 0; b < 9; ++b) {
    float acc = score_b1[j];
#pragma unroll
    for (int d = 0; d < 20; ++d)
      acc = fmaf(width_table[b*20 + d], score_W1[(3*AD + d)*HID + j], acc);
    WT[b*RS + j] = acc;
  }
}

#define PS 168   // bf16 LDS row stride (336B = 21*16, spreads banks)

// ---------------------------------------------------------------------------
// k_attn2: per-token attention logit. 80 tokens/block.
//   AH(fp32) -> bf16 LDS, MFMA vs AW2t, fused relu(+b2)*W3 reduce -> ATT.
// ---------------------------------------------------------------------------
__global__ __launch_bounds__(640) void k_attn2(
    const unsigned short* __restrict__ AW2t,
    const float* __restrict__ ab2, const float* __restrict__ aw3,
    const float* __restrict__ ab3, float* __restrict__ ws) {
  const int t0 = blockIdx.x * 80;
  const int t = threadIdx.x, lane = t & 63, wv = t >> 6;
  const int r = lane & 15, g = lane >> 4;
  __shared__ unsigned short sH[80 * PS];
  __shared__ float red[80][10];
  const float* AH = ws + OFF_AH;

  for (int u = t; u < 80*160; u += 640) {
    int row = u / 160, jj = u - row*160;
    int tok = t0 + row;
    float v = (jj < HID && tok < T_TOK) ? AH[(size_t)tok*RS + jj] : 0.f;
    sH[row*PS + jj] = f2bf(v);
  }
  __syncthreads();

  const int jt = wv;
  bf16x8 Af[5];
#pragma unroll
  for (int kc = 0; kc < 5; ++kc)
    Af[kc] = *(const bf16x8*)&AW2t[(size_t)(jt*16 + r)*160 + kc*32 + g*8];
  f32x4 acc[5];
#pragma unroll
  for (int nt = 0; nt < 5; ++nt) acc[nt] = (f32x4){0.f,0.f,0.f,0.f};
#pragma unroll
  for (int nt = 0; nt < 5; ++nt)
#pragma unroll
    for (int kc = 0; kc < 5; ++kc) {
      bf16x8 Bf = *(const bf16x8*)&sH[(nt*16 + r)*PS + kc*32 + g*8];
      acc[nt] = __builtin_amdgcn_mfma_f32_16x16x32_bf16(Af[kc], Bf, acc[nt], 0, 0, 0);
    }

  float b2v[4], w3v[4];
#pragma unroll
  for (int q = 0; q < 4; ++q) {
    int j = jt*16 + g*4 + q;
    b2v[q] = (j < HID) ? ab2[j] : 0.f;
    w3v[q] = (j < HID) ? aw3[j] : 0.f;
  }
#pragma unroll
  for (int nt = 0; nt < 5; ++nt) {
    float p = 0.f;
#pragma unroll
    for (int q = 0; q < 4; ++q)
      p += fmaxf(acc[nt][q] + b2v[q], 0.f) * w3v[q];
    p += __shfl_xor(p, 16);
    p += __shfl_xor(p, 32);
    if (g == 0) red[nt*16 + r][wv] = p;
  }
  __syncthreads();
  if (t < 80 && t0 + t < T_TOK) {
    float s = ab3[0];
#pragma unroll
    for (int w = 0; w < 10; ++w) s += red[t][w];
    ws[OFF_ATT + t0 + t] = s;
  }
}

// ---------------------------------------------------------------------------
// k_span: fused H1-build (bf16, in LDS) + layer-2 MFMA + W3 reduce -> out.
//   8 starts (80 spans) per block, 10 waves, wave w owns j-tile w.
// ---------------------------------------------------------------------------
#define SPB 8
__global__ __launch_bounds__(640) void k_span(
    const unsigned short* __restrict__ W2t,
    const float* __restrict__ sb2, const float* __restrict__ sw3,
    const float* __restrict__ sb3,
    const float* __restrict__ ws, float* __restrict__ out) {
  const int i1b = blockIdx.x * SPB;
  const int t = threadIdx.x, lane = t & 63, wv = t >> 6;
  const int r = lane & 15, g = lane >> 4;
  __shared__ unsigned short sH[80 * PS];
  __shared__ float sE[SPB][10], sI[SPB][10];
  __shared__ float red[80][10];
  const float* ATT = ws + OFF_ATT;

  if (t < SPB) {
    int i1 = i1b + t;
    if (i1 < NSTART) {
      float a[10];
#pragma unroll
      for (int l = 0; l < 10; ++l) a[l] = ATT[i1 + l];
      float M = a[0];
#pragma unroll
      for (int l = 1; l < 10; ++l) M = fmaxf(M, a[l]);
      float D = 0.f;
#pragma unroll
      for (int l = 0; l < 10; ++l) {
        float e = expf(a[l] - M);
        D += e;
        sE[t][l] = e;
        sI[t][l] = 1.f / D;
      }
    } else {
#pragma unroll
      for (int l = 0; l < 10; ++l) { sE[t][l] = 0.f; sI[t][l] = 0.f; }
    }
  }
  __syncthreads();

  const float* SA = ws + OFF_SA;
  const float* SBp = ws + OFF_SB;
  const float* EC = ws + OFF_EC;
  const float* WT = ws + OFF_WT;
  const int binrow[10] = {1,2,3,4,4,4,4,5,5,5};

#pragma unroll
  for (int rep = 0; rep < 2; ++rep) {
    int u = rep*640 + t;                 // 0..1279
    int sl = u / 160, jj = u - sl*160;
    int i1 = i1b + sl;
    if (jj < HID) {
      float sa = SA[(size_t)i1*RS + jj];
      float rs = 0.f;
#pragma unroll
      for (int l = 0; l < 10; ++l) {
        // i1+l may reach 2048 for the one invalid start; that row aliases the
        // next ws region (finite, written) and feeds only a discarded span.
        rs = fmaf(sE[sl][l], EC[(size_t)(i1+l)*RS + jj], rs);
        float h = sa + SBp[(size_t)(i1+l)*RS + jj] + WT[binrow[l]*RS + jj]
                + rs * sI[sl][l];
        sH[(sl*10 + l)*PS + jj] = f2bf(fmaxf(h, 0.f));
      }
    } else {
#pragma unroll
      for (int l = 0; l < 10; ++l) sH[(sl*10 + l)*PS + jj] = 0;
    }
  }
  __syncthreads();

  const int jt = wv;
  bf16x8 Af[5];
#pragma unroll
  for (int kc = 0; kc < 5; ++kc)
    Af[kc] = *(const bf16x8*)&W2t[(size_t)(jt*16 + r)*160 + kc*32 + g*8];
  f32x4 acc[5];
#pragma unroll
  for (int nt = 0; nt < 5; ++nt) acc[nt] = (f32x4){0.f,0.f,0.f,0.f};
#pragma unroll
  for (int nt = 0; nt < 5; ++nt)
#pragma unroll
    for (int kc = 0; kc < 5; ++kc) {
      bf16x8 Bf = *(const bf16x8*)&sH[(nt*16 + r)*PS + kc*32 + g*8];
      acc[nt] = __builtin_amdgcn_mfma_f32_16x16x32_bf16(Af[kc], Bf, acc[nt], 0, 0, 0);
    }

  float b2v[4], w3v[4];
#pragma unroll
  for (int q = 0; q < 4; ++q) {
    int j = jt*16 + g*4 + q;
    b2v[q] = (j < HID) ? sb2[j] : 0.f;
    w3v[q] = (j < HID) ? sw3[j] : 0.f;
  }
#pragma unroll
  for (int nt = 0; nt < 5; ++nt) {
    float p = 0.f;
#pragma unroll
    for (int q = 0; q < 4; ++q)
      p += fmaxf(acc[nt][q] + b2v[q], 0.f) * w3v[q];
    p += __shfl_xor(p, 16);
    p += __shfl_xor(p, 32);
    if (g == 0) red[nt*16 + r][wv] = p;
  }
  __syncthreads();
  if (t < 80) {
    int ng = i1b*10 + t;
    if (ng < NSPAN) {
      float s = sb3[0];
#pragma unroll
      for (int w = 0; w < 10; ++w) s += red[t][w];
      out[ng] = s;
    }
  }
}

extern "C" void kernel_launch(void* const* d_in, const int* in_sizes, int n_in,
                              void* d_out, int out_size, void* d_ws, size_t ws_size,
                              hipStream_t stream) {
  const float* states      = (const float*)d_in[0];
  const float* embeds      = (const float*)d_in[1];
  const float* attn_W1     = (const float*)d_in[2];
  const float* attn_b1     = (const float*)d_in[3];
  const float* attn_W2     = (const float*)d_in[4];
  const float* attn_b2     = (const float*)d_in[5];
  const float* attn_W3     = (const float*)d_in[6];
  const float* attn_b3     = (const float*)d_in[7];
  const float* width_table = (const float*)d_in[8];
  const float* score_W1    = (const float*)d_in[9];
  const float* score_b1    = (const float*)d_in[10];
  const float* score_W2    = (const float*)d_in[11];
  const float* score_b2    = (const float*)d_in[12];
  const float* score_W3    = (const float*)d_in[13];
  const float* score_b3    = (const float*)d_in[14];
  float* out = (float*)d_out;
  float* ws  = (float*)d_ws;

  unsigned short* Sb   = (unsigned short*)(ws + OFF_BF16);
  unsigned short* Eb   = Sb + SB_SHORTS;
  unsigned short* Wt   = Eb + SB_SHORTS;
  unsigned short* W2t  = Wt + 640*AD;
  unsigned short* AW2t = W2t + 25600;

  k_cvt   <<<2048, 256, 0, stream>>>(states, embeds, Sb);
  k_packw <<<32,   256, 0, stream>>>(attn_W1, score_W1, Wt);
  k_packw2<<<200,  256, 0, stream>>>(score_W2, attn_W2, W2t, AW2t);
  k_wt    <<<1,    192, 0, stream>>>(width_table, score_W1, score_b1, ws);
  k_gemm  <<<dim3(T_TOK/BM, 8), 320, 0, stream>>>(Sb, Eb, Wt, attn_b1, ws);
  k_attn2 <<<(T_TOK+79)/80, 640, 0, stream>>>(AW2t, attn_b2, attn_W3, attn_b3, ws);
  k_span  <<<(NSTART+SPB-1)/SPB, 640, 0, stream>>>(W2t, score_b2, score_W3, score_b3, ws, out);
}

// Round 4
// 56.195 us; speedup vs baseline: 3.7890x; 1.2699x over previous
//
#include <hip/hip_runtime.h>

#define T_TOK 2048
#define AD    1024
#define HID   150
#define LW    10
#define NSTART (T_TOK - LW + 1)   // 2039
#define NSPAN  (NSTART * LW)      // 20390
#define RS    152                 // padded fp32 row stride

// workspace offsets (in floats)
#define OFF_AH  0
#define OFF_SA  (OFF_AH + T_TOK*RS)
#define OFF_SB  (OFF_SA + T_TOK*RS)
#define OFF_EC  (OFF_SB + T_TOK*RS)
#define OFF_WT  (OFF_EC + T_TOK*RS)     // 16 rows reserved
#define OFF_ATT (OFF_WT + 16*RS)
#define OFF_BF16 (OFF_ATT + T_TOK)
#define SB_SHORTS (T_TOK*AD)            // 2,097,152

typedef __attribute__((ext_vector_type(8))) short bf16x8;
typedef __attribute__((ext_vector_type(4))) float f32x4;

__device__ inline unsigned short f2bf(float f) {
  unsigned u = __builtin_bit_cast(unsigned, f);
  u += 0x7fff + ((u >> 16) & 1);        // RNE
  return (unsigned short)(u >> 16);
}

__device__ inline void gld16(const void* g, void* l) {
  __builtin_amdgcn_global_load_lds(
      (const __attribute__((address_space(1))) unsigned int*)g,
      (__attribute__((address_space(3))) unsigned int*)l, 16, 0, 0);
}

// ---------------------------------------------------------------------------
// k_prep: fused prep (all branches independent):
//   blocks [0,2048):    states+embeds fp32 -> bf16
//   blocks [2048,2080): W1 pack-transpose -> Wt[640][1024] bf16
//   blocks [2080,2280): W2 pack-transpose -> W2t/AW2t [160][160] bf16
//   block  2280:        WT width-bucket rows
// ---------------------------------------------------------------------------
__global__ __launch_bounds__(256) void k_prep(
    const float* __restrict__ st, const float* __restrict__ em,
    const float* __restrict__ aw1, const float* __restrict__ sw1,
    const float* __restrict__ sw2, const float* __restrict__ aw2,
    const float* __restrict__ width_table, const float* __restrict__ score_b1,
    unsigned short* __restrict__ Sb, unsigned short* __restrict__ Wt,
    unsigned short* __restrict__ W2t, unsigned short* __restrict__ AW2t,
    float* __restrict__ ws) {
  __shared__ unsigned short T[152*136];
  const int b = blockIdx.x, t = threadIdx.x;

  if (b < 2048) {                       // ---- cvt
    int i = b * 256 + t;
    const float* src; unsigned short* dst; int idx;
    if (i < SB_SHORTS/8) { src = st; idx = i; dst = Sb; }
    else { src = em; idx = i - SB_SHORTS/8; dst = Sb + SB_SHORTS; }
    float4 a = ((const float4*)src)[idx*2];
    float4 c = ((const float4*)src)[idx*2+1];
    uint4 o;
    o.x = (unsigned)f2bf(a.x) | ((unsigned)f2bf(a.y) << 16);
    o.y = (unsigned)f2bf(a.z) | ((unsigned)f2bf(a.w) << 16);
    o.z = (unsigned)f2bf(c.x) | ((unsigned)f2bf(c.y) << 16);
    o.w = (unsigned)f2bf(c.z) | ((unsigned)f2bf(c.w) << 16);
    *(uint4*)(dst + (size_t)idx*8) = o;
  } else if (b < 2080) {                // ---- packw (W1 transpose)
    const int b2 = b - 2048, grp = b2 >> 3, kt = b2 & 7;
    const float* src = (grp == 0) ? aw1 : sw1 + (size_t)(grp-1)*AD*HID;
    const int k0 = kt * 128;
    for (int idx = t; idx < 128*152; idx += 256) {
      int kl = idx / 152, j = idx - kl*152;
      float v = (j < HID) ? src[(size_t)(k0+kl)*HID + j] : 0.f;
      T[j*136 + kl] = f2bf(v);
    }
    __syncthreads();
    for (int u = t; u < 160*16; u += 256) {
      int jj = u >> 4, kc = u & 15;
      bf16x8 v;
      if (jj < 152) v = *(const bf16x8*)&T[jj*136 + kc*8];
      else          v = (bf16x8){0,0,0,0,0,0,0,0};
      *(bf16x8*)&Wt[(size_t)(grp*160 + jj)*AD + k0 + kc*8] = v;
    }
  } else if (b < 2280) {                // ---- packw2 (W2 transpose, both MLPs)
    int idx = (b - 2080) * 256 + t;     // 0..51199
    const float* src; unsigned short* dst; int u;
    if (idx < 25600) { src = sw2; dst = W2t; u = idx; }
    else             { src = aw2; dst = AW2t; u = idx - 25600; }
    int j = u / 160, k = u - j*160;
    float v = (j < HID && k < HID) ? src[(size_t)k*HID + j] : 0.f;
    dst[u] = f2bf(v);
  } else {                              // ---- wt (width buckets)
    const int j = t;
    if (j < HID) {
      float* WT = ws + OFF_WT;
      for (int bb = 0; bb < 9; ++bb) {
        float acc = score_b1[j];
#pragma unroll
        for (int d = 0; d < 20; ++d)
          acc = fmaf(width_table[bb*20 + d], sw1[(size_t)(3*AD + d)*HID + j], acc);
        WT[bb*RS + j] = acc;
      }
    }
  }
}

// ---------------------------------------------------------------------------
// k_gemm: layer-1 bf16 MFMA (AH/SA/SB/EC), validated structure
// ---------------------------------------------------------------------------
#define BM 32
#define KS 64
__global__ __launch_bounds__(320) void k_gemm(
    const unsigned short* __restrict__ Sb, const unsigned short* __restrict__ Eb,
    const unsigned short* __restrict__ Wt, const float* __restrict__ attn_b1,
    float* __restrict__ ws) {
  const int m0   = blockIdx.x * BM;
  const int s    = blockIdx.y >> 1;
  const int half = blockIdx.y & 1;
  const int tid  = threadIdx.x;
  const int lane = tid & 63, wv = tid >> 6;

  __shared__ unsigned short lA[2][BM*KS];
  __shared__ unsigned short lB[2][80*KS];

  const unsigned short* Ag = (s < 3 ? Sb : Eb) + (size_t)m0 * AD;
  const unsigned short* Bg = Wt + (size_t)(s*160 + half*80) * AD;

  f32x4 acc0 = {0.f,0.f,0.f,0.f}, acc1 = {0.f,0.f,0.f,0.f};

  auto stage = [&](int kb, int buf) {
    for (int seg = wv; seg < 14; seg += 5) {
      if (seg < 10) {
        int c = seg*64 + lane;
        int row = c >> 3, ch = c & 7;
        gld16(Bg + (size_t)row*AD + kb + ((ch ^ (row & 7)) << 3), &lB[buf][seg*512]);
      } else {
        int c = (seg-10)*64 + lane;
        int row = c >> 3, ch = c & 7;
        gld16(Ag + (size_t)row*AD + kb + ((ch ^ (row & 7)) << 3), &lA[buf][(seg-10)*512]);
      }
    }
  };

  stage(0, 0);
  int buf = 0;
  const int r = lane & 15, g = lane >> 4;
  const int rx = wv*16 + r;
  const int sw = r & 7;

  for (int kk = 0; kk < 16; ++kk) {
    __syncthreads();
    if (kk < 15) stage((kk+1)*KS, buf ^ 1);
#pragma unroll
    for (int z = 0; z < 2; ++z) {
      const int cz = z*4 + g;
      bf16x8 X  = *(const bf16x8*)&lB[buf][rx*KS      + ((cz ^ sw) << 3)];
      bf16x8 Y0 = *(const bf16x8*)&lA[buf][r*KS       + ((cz ^ sw) << 3)];
      bf16x8 Y1 = *(const bf16x8*)&lA[buf][(16+r)*KS  + ((cz ^ sw) << 3)];
      acc0 = __builtin_amdgcn_mfma_f32_16x16x32_bf16(X, Y0, acc0, 0, 0, 0);
      acc1 = __builtin_amdgcn_mfma_f32_16x16x32_bf16(X, Y1, acc1, 0, 0, 0);
    }
    buf ^= 1;
  }

  const int jn = half*80 + wv*16 + g*4;
  float* Cp = ws + (s==0 ? OFF_AH : s==1 ? OFF_SA : s==2 ? OFF_SB : OFF_EC);
#pragma unroll
  for (int f = 0; f < 2; ++f) {
    int m = m0 + f*16 + r;
    f32x4 a = f ? acc1 : acc0;
    if (s == 0) {
#pragma unroll
      for (int q = 0; q < 4; ++q)
        if (jn + q < HID) a[q] = fmaxf(a[q] + attn_b1[jn+q], 0.f);
    }
    float* d = Cp + (size_t)m*RS + jn;
    if (jn + 3 < HID) *(f32x4*)d = a;
    else {
#pragma unroll
      for (int q = 0; q < 4; ++q) if (jn + q < HID) d[q] = a[q];
    }
  }
}

#define PS 168   // bf16 LDS row stride

// ---------------------------------------------------------------------------
// k_span: per block of 8 starts (80 spans):
//   A) local attn logits for its 17-token window (bf16 MFMA vs AW2t)
//   B) prefix softmax per start
//   C) H1 build (bf16) into LDS
//   D) layer-2 MFMA vs W2t + fused relu*W3 reduce -> out
// ---------------------------------------------------------------------------
#define SPB 8
__global__ __launch_bounds__(640) void k_span(
    const unsigned short* __restrict__ W2t,
    const unsigned short* __restrict__ AW2t,
    const float* __restrict__ ab2, const float* __restrict__ aw3,
    const float* __restrict__ ab3,
    const float* __restrict__ sb2, const float* __restrict__ sw3,
    const float* __restrict__ sb3,
    const float* __restrict__ ws, float* __restrict__ out) {
  const int i1b = blockIdx.x * SPB;
  const int t = threadIdx.x, lane = t & 63, wv = t >> 6;
  const int r = lane & 15, g = lane >> 4;
  __shared__ unsigned short sH[80 * PS];
  __shared__ float red[80][10];
  __shared__ float sATT[32];
  __shared__ float sE[SPB][10], sI[SPB][10];
  const float* AH = ws + OFF_AH;

  // ---- Phase A: attention logits for tokens i1b..i1b+16
  for (int u = t; u < 32*160; u += 640) {
    int row = u / 160, jj = u - row*160;
    int tok = i1b + row;
    float v = (row < 17 && jj < HID && tok < T_TOK) ? AH[(size_t)tok*RS + jj] : 0.f;
    sH[row*PS + jj] = f2bf(v);
  }
  __syncthreads();
  {
    const int jt = wv;
    bf16x8 Af[5];
#pragma unroll
    for (int kc = 0; kc < 5; ++kc)
      Af[kc] = *(const bf16x8*)&AW2t[(size_t)(jt*16 + r)*160 + kc*32 + g*8];
    f32x4 acc[2];
#pragma unroll
    for (int nt = 0; nt < 2; ++nt) acc[nt] = (f32x4){0.f,0.f,0.f,0.f};
#pragma unroll
    for (int nt = 0; nt < 2; ++nt)
#pragma unroll
      for (int kc = 0; kc < 5; ++kc) {
        bf16x8 Bf = *(const bf16x8*)&sH[(nt*16 + r)*PS + kc*32 + g*8];
        acc[nt] = __builtin_amdgcn_mfma_f32_16x16x32_bf16(Af[kc], Bf, acc[nt], 0, 0, 0);
      }
    float b2v[4], w3v[4];
#pragma unroll
    for (int q = 0; q < 4; ++q) {
      int j = jt*16 + g*4 + q;
      b2v[q] = (j < HID) ? ab2[j] : 0.f;
      w3v[q] = (j < HID) ? aw3[j] : 0.f;
    }
#pragma unroll
    for (int nt = 0; nt < 2; ++nt) {
      float p = 0.f;
#pragma unroll
      for (int q = 0; q < 4; ++q)
        p += fmaxf(acc[nt][q] + b2v[q], 0.f) * w3v[q];
      p += __shfl_xor(p, 16);
      p += __shfl_xor(p, 32);
      if (g == 0) red[nt*16 + r][wv] = p;
    }
  }
  __syncthreads();
  if (t < 32) {
    float s = ab3[0];
#pragma unroll
    for (int w = 0; w < 10; ++w) s += red[t][w];
    sATT[t] = s;
  }
  __syncthreads();

  // ---- Phase B: prefix softmax per start
  if (t < SPB) {
    int i1 = i1b + t;
    if (i1 < NSTART) {
      float a[10];
#pragma unroll
      for (int l = 0; l < 10; ++l) a[l] = sATT[t + l];
      float M = a[0];
#pragma unroll
      for (int l = 1; l < 10; ++l) M = fmaxf(M, a[l]);
      float D = 0.f;
#pragma unroll
      for (int l = 0; l < 10; ++l) {
        float e = expf(a[l] - M);
        D += e;
        sE[t][l] = e;
        sI[t][l] = 1.f / D;
      }
    } else {
#pragma unroll
      for (int l = 0; l < 10; ++l) { sE[t][l] = 0.f; sI[t][l] = 0.f; }
    }
  }
  __syncthreads();

  // ---- Phase C: build H1 (bf16) in LDS
  const float* SA = ws + OFF_SA;
  const float* SBp = ws + OFF_SB;
  const float* EC = ws + OFF_EC;
  const float* WT = ws + OFF_WT;
  const int binrow[10] = {1,2,3,4,4,4,4,5,5,5};

#pragma unroll
  for (int rep = 0; rep < 2; ++rep) {
    int u = rep*640 + t;                 // 0..1279
    int sl = u / 160, jj = u - sl*160;
    int i1 = i1b + sl;
    if (jj < HID) {
      float sa = SA[(size_t)i1*RS + jj];
      float rs = 0.f;
#pragma unroll
      for (int l = 0; l < 10; ++l) {
        // i1+l may reach 2048 for the one invalid start; that row aliases the
        // next ws region (finite, written) and feeds only a discarded span.
        rs = fmaf(sE[sl][l], EC[(size_t)(i1+l)*RS + jj], rs);
        float h = sa + SBp[(size_t)(i1+l)*RS + jj] + WT[binrow[l]*RS + jj]
                + rs * sI[sl][l];
        sH[(sl*10 + l)*PS + jj] = f2bf(fmaxf(h, 0.f));
      }
    } else {
#pragma unroll
      for (int l = 0; l < 10; ++l) sH[(sl*10 + l)*PS + jj] = 0;
    }
  }
  __syncthreads();

  // ---- Phase D: layer-2 MFMA + fused W3 reduce
  const int jt = wv;
  bf16x8 Af[5];
#pragma unroll
  for (int kc = 0; kc < 5; ++kc)
    Af[kc] = *(const bf16x8*)&W2t[(size_t)(jt*16 + r)*160 + kc*32 + g*8];
  f32x4 acc[5];
#pragma unroll
  for (int nt = 0; nt < 5; ++nt) acc[nt] = (f32x4){0.f,0.f,0.f,0.f};
#pragma unroll
  for (int nt = 0; nt < 5; ++nt)
#pragma unroll
    for (int kc = 0; kc < 5; ++kc) {
      bf16x8 Bf = *(const bf16x8*)&sH[(nt*16 + r)*PS + kc*32 + g*8];
      acc[nt] = __builtin_amdgcn_mfma_f32_16x16x32_bf16(Af[kc], Bf, acc[nt], 0, 0, 0);
    }

  float b2v[4], w3v[4];
#pragma unroll
  for (int q = 0; q < 4; ++q) {
    int j = jt*16 + g*4 + q;
    b2v[q] = (j < HID) ? sb2[j] : 0.f;
    w3v[q] = (j < HID) ? sw3[j] : 0.f;
  }
#pragma unroll
  for (int nt = 0; nt < 5; ++nt) {
    float p = 0.f;
#pragma unroll
    for (int q = 0; q < 4; ++q)
      p += fmaxf(acc[nt][q] + b2v[q], 0.f) * w3v[q];
    p += __shfl_xor(p, 16);
    p += __shfl_xor(p, 32);
    if (g == 0) red[nt*16 + r][wv] = p;
  }
  __syncthreads();
  if (t < 80) {
    int ng = i1b*10 + t;
    if (ng < NSPAN) {
      float s = sb3[0];
#pragma unroll
      for (int w = 0; w < 10; ++w) s += red[t][w];
      out[ng] = s;
    }
  }
}

extern "C" void kernel_launch(void* const* d_in, const int* in_sizes, int n_in,
                              void* d_out, int out_size, void* d_ws, size_t ws_size,
                              hipStream_t stream) {
  const float* states      = (const float*)d_in[0];
  const float* embeds      = (const float*)d_in[1];
  const float* attn_W1     = (const float*)d_in[2];
  const float* attn_b1     = (const float*)d_in[3];
  const float* attn_W2     = (const float*)d_in[4];
  const float* attn_b2     = (const float*)d_in[5];
  const float* attn_W3     = (const float*)d_in[6];
  const float* attn_b3     = (const float*)d_in[7];
  const float* width_table = (const float*)d_in[8];
  const float* score_W1    = (const float*)d_in[9];
  const float* score_b1    = (const float*)d_in[10];
  const float* score_W2    = (const float*)d_in[11];
  const float* score_b2    = (const float*)d_in[12];
  const float* score_W3    = (const float*)d_in[13];
  const float* score_b3    = (const float*)d_in[14];
  float* out = (float*)d_out;
  float* ws  = (float*)d_ws;

  unsigned short* Sb   = (unsigned short*)(ws + OFF_BF16);
  unsigned short* Eb   = Sb + SB_SHORTS;
  unsigned short* Wt   = Eb + SB_SHORTS;
  unsigned short* W2t  = Wt + 640*AD;
  unsigned short* AW2t = W2t + 25600;

  k_prep<<<2281, 256, 0, stream>>>(states, embeds, attn_W1, score_W1,
                                   score_W2, attn_W2, width_table, score_b1,
                                   Sb, Wt, W2t, AW2t, ws);
  k_gemm<<<dim3(T_TOK/BM, 8), 320, 0, stream>>>(Sb, Eb, Wt, attn_b1, ws);
  k_span<<<(NSTART+SPB-1)/SPB, 640, 0, stream>>>(W2t, AW2t,
                                   attn_b2, attn_W3, attn_b3,
                                   score_b2, score_W3, score_b3, ws, out);
}

// Round 5
// 43.092 us; speedup vs baseline: 4.9410x; 1.3040x over previous
//
#include <hip/hip_runtime.h>

#define T_TOK 2048
#define AD    1024
#define HID   150
#define LW    10
#define NSTART (T_TOK - LW + 1)   // 2039
#define NSPAN  (NSTART * LW)      // 20390
#define RS    152                 // padded fp32 row stride

// workspace offsets (in floats)
#define OFF_AH  0
#define OFF_SA  (OFF_AH + T_TOK*RS)
#define OFF_SB  (OFF_SA + T_TOK*RS)
#define OFF_EC  (OFF_SB + T_TOK*RS)
#define OFF_WT  (OFF_EC + T_TOK*RS)     // 16 rows reserved
#define OFF_ATT (OFF_WT + 16*RS)
#define OFF_BF16 (OFF_ATT + T_TOK)

typedef __attribute__((ext_vector_type(8))) short bf16x8;
typedef __attribute__((ext_vector_type(4))) float f32x4;

__device__ inline unsigned short f2bf(float f) {
  unsigned u = __builtin_bit_cast(unsigned, f);
  u += 0x7fff + ((u >> 16) & 1);        // RNE
  return (unsigned short)(u >> 16);
}

__device__ inline unsigned cvt2(float lo, float hi) {   // packed bf16x2, RNE
  unsigned r;
  asm("v_cvt_pk_bf16_f32 %0, %1, %2" : "=v"(r) : "v"(lo), "v"(hi));
  return r;
}

__device__ inline void gld16(const void* g, void* l) {
  __builtin_amdgcn_global_load_lds(
      (const __attribute__((address_space(1))) unsigned int*)g,
      (__attribute__((address_space(3))) unsigned int*)l, 16, 0, 0);
}

// ---------------------------------------------------------------------------
// k_pack: weight packing only.
//   blocks [0,64):    W1 pack-transpose -> Wt[640][1024] bf16 (22KB LDS tile)
//   blocks [64,264):  W2 pack-transpose -> W2t/AW2t [160][160] bf16
//   block  264:       WT width-bucket rows (fp32)
// ---------------------------------------------------------------------------
__global__ __launch_bounds__(256) void k_pack(
    const float* __restrict__ aw1, const float* __restrict__ sw1,
    const float* __restrict__ sw2, const float* __restrict__ aw2,
    const float* __restrict__ width_table, const float* __restrict__ score_b1,
    unsigned short* __restrict__ Wt,
    unsigned short* __restrict__ W2t, unsigned short* __restrict__ AW2t,
    float* __restrict__ ws) {
  __shared__ unsigned short T[152*72];    // 21.9 KB
  const int b = blockIdx.x, t = threadIdx.x;

  if (b < 64) {                         // ---- W1 transpose: grp in [0,4), kt in [0,16)
    const int grp = b >> 4, kt = b & 15;
    const float* src = (grp == 0) ? aw1 : sw1 + (size_t)(grp-1)*AD*HID;
    const int k0 = kt * 64;
    for (int idx = t; idx < 64*152; idx += 256) {
      int kl = idx / 152, j = idx - kl*152;
      float v = (j < HID) ? src[(size_t)(k0+kl)*HID + j] : 0.f;
      T[j*72 + kl] = f2bf(v);
    }
    __syncthreads();
    for (int u = t; u < 160*8; u += 256) {
      int jj = u >> 3, kc = u & 7;
      bf16x8 v;
      if (jj < 152) v = *(const bf16x8*)&T[jj*72 + kc*8];
      else          v = (bf16x8){0,0,0,0,0,0,0,0};
      *(bf16x8*)&Wt[(size_t)(grp*160 + jj)*AD + k0 + kc*8] = v;
    }
  } else if (b < 264) {                 // ---- W2 packs (both MLPs)
    int idx = (b - 64) * 256 + t;       // 0..51199
    const float* src; unsigned short* dst; int u;
    if (idx < 25600) { src = sw2; dst = W2t; u = idx; }
    else             { src = aw2; dst = AW2t; u = idx - 25600; }
    int j = u / 160, k = u - j*160;
    float v = (j < HID && k < HID) ? src[(size_t)k*HID + j] : 0.f;
    dst[u] = f2bf(v);
  } else {                              // ---- WT width-bucket rows
    const int j = t;
    if (j < HID) {
      float* WT = ws + OFF_WT;
      for (int bb = 0; bb < 9; ++bb) {
        float acc = score_b1[j];
#pragma unroll
        for (int d = 0; d < 20; ++d)
          acc = fmaf(width_table[bb*20 + d], sw1[(size_t)(3*AD + d)*HID + j], acc);
        WT[bb*RS + j] = acc;
      }
    }
  }
}

// ---------------------------------------------------------------------------
// k_gemm: layer-1 bf16 MFMA. A-operand read DIRECTLY from fp32 states/embeds:
//   reg-staged (global fp32 -> v_cvt_pk_bf16_f32 -> ds_write_b128), same LDS
//   placement/swizzle as before. B (weights) staged via global_load_lds.
// ---------------------------------------------------------------------------
#define BM 32
#define KS 64
__global__ __launch_bounds__(320) void k_gemm(
    const float* __restrict__ st, const float* __restrict__ em,
    const unsigned short* __restrict__ Wt, const float* __restrict__ attn_b1,
    float* __restrict__ ws) {
  const int m0   = blockIdx.x * BM;
  const int s    = blockIdx.y >> 1;
  const int half = blockIdx.y & 1;
  const int tid  = threadIdx.x;
  const int lane = tid & 63, wv = tid >> 6;

  __shared__ unsigned short lA[2][BM*KS];   // 2 x 4KB
  __shared__ unsigned short lB[2][80*KS];   // 2 x 10KB

  const float* Ag = (s < 3 ? st : em) + (size_t)m0 * AD;
  const unsigned short* Bg = Wt + (size_t)(s*160 + half*80) * AD;

  f32x4 acc0 = {0.f,0.f,0.f,0.f}, acc1 = {0.f,0.f,0.f,0.f};

  auto stageB = [&](int kb, int buf) {
    for (int seg = wv; seg < 10; seg += 5) {
      int c = seg*64 + lane;
      int row = c >> 3, ch = c & 7;
      gld16(Bg + (size_t)row*AD + kb + ((ch ^ (row & 7)) << 3), &lB[buf][seg*512]);
    }
  };
  auto stageA = [&](int kb, int buf) {
    if (tid < 256) {                    // chunk = tid: row = tid>>3, ch = tid&7
      int row = tid >> 3, ch = tid & 7;
      const float* src = Ag + (size_t)row*AD + kb + ((ch ^ (row & 7)) << 3);
      float4 a = *(const float4*)src;
      float4 c = *(const float4*)(src + 4);
      uint4 o;
      o.x = cvt2(a.x, a.y); o.y = cvt2(a.z, a.w);
      o.z = cvt2(c.x, c.y); o.w = cvt2(c.z, c.w);
      *(uint4*)&lA[buf][tid*8] = o;     // linear: chunk*16B (matches read swizzle)
    }
  };

  stageB(0, 0);
  stageA(0, 0);
  int buf = 0;
  const int r = lane & 15, g = lane >> 4;
  const int rx = wv*16 + r;
  const int sw = r & 7;

  for (int kk = 0; kk < 16; ++kk) {
    __syncthreads();
    if (kk < 15) { stageB((kk+1)*KS, buf ^ 1); stageA((kk+1)*KS, buf ^ 1); }
#pragma unroll
    for (int z = 0; z < 2; ++z) {
      const int cz = z*4 + g;
      bf16x8 X  = *(const bf16x8*)&lB[buf][rx*KS      + ((cz ^ sw) << 3)];
      bf16x8 Y0 = *(const bf16x8*)&lA[buf][r*KS       + ((cz ^ sw) << 3)];
      bf16x8 Y1 = *(const bf16x8*)&lA[buf][(16+r)*KS  + ((cz ^ sw) << 3)];
      acc0 = __builtin_amdgcn_mfma_f32_16x16x32_bf16(X, Y0, acc0, 0, 0, 0);
      acc1 = __builtin_amdgcn_mfma_f32_16x16x32_bf16(X, Y1, acc1, 0, 0, 0);
    }
    buf ^= 1;
  }

  const int jn = half*80 + wv*16 + g*4;
  float* Cp = ws + (s==0 ? OFF_AH : s==1 ? OFF_SA : s==2 ? OFF_SB : OFF_EC);
#pragma unroll
  for (int f = 0; f < 2; ++f) {
    int m = m0 + f*16 + r;
    f32x4 a = f ? acc1 : acc0;
    if (s == 0) {
#pragma unroll
      for (int q = 0; q < 4; ++q)
        if (jn + q < HID) a[q] = fmaxf(a[q] + attn_b1[jn+q], 0.f);
    }
    float* d = Cp + (size_t)m*RS + jn;
    if (jn + 3 < HID) *(f32x4*)d = a;
    else {
#pragma unroll
      for (int q = 0; q < 4; ++q) if (jn + q < HID) d[q] = a[q];
    }
  }
}

#define PS 168   // bf16 LDS row stride

// ---------------------------------------------------------------------------
// k_span: per block of 8 starts (80 spans):
//   A) local attn logits for its 17-token window (bf16 MFMA vs AW2t)
//   B) prefix softmax per start
//   C) H1 build (bf16) into LDS
//   D) layer-2 MFMA vs W2t + fused relu*W3 reduce -> out
// ---------------------------------------------------------------------------
#define SPB 8
__global__ __launch_bounds__(640) void k_span(
    const unsigned short* __restrict__ W2t,
    const unsigned short* __restrict__ AW2t,
    const float* __restrict__ ab2, const float* __restrict__ aw3,
    const float* __restrict__ ab3,
    const float* __restrict__ sb2, const float* __restrict__ sw3,
    const float* __restrict__ sb3,
    const float* __restrict__ ws, float* __restrict__ out) {
  const int i1b = blockIdx.x * SPB;
  const int t = threadIdx.x, lane = t & 63, wv = t >> 6;
  const int r = lane & 15, g = lane >> 4;
  __shared__ unsigned short sH[80 * PS];
  __shared__ float red[80][10];
  __shared__ float sATT[32];
  __shared__ float sE[SPB][10], sI[SPB][10];
  const float* AH = ws + OFF_AH;

  // ---- Phase A: attention logits for tokens i1b..i1b+16
  for (int u = t; u < 32*160; u += 640) {
    int row = u / 160, jj = u - row*160;
    int tok = i1b + row;
    float v = (row < 17 && jj < HID && tok < T_TOK) ? AH[(size_t)tok*RS + jj] : 0.f;
    sH[row*PS + jj] = f2bf(v);
  }
  __syncthreads();
  {
    const int jt = wv;
    bf16x8 Af[5];
#pragma unroll
    for (int kc = 0; kc < 5; ++kc)
      Af[kc] = *(const bf16x8*)&AW2t[(size_t)(jt*16 + r)*160 + kc*32 + g*8];
    f32x4 acc[2];
#pragma unroll
    for (int nt = 0; nt < 2; ++nt) acc[nt] = (f32x4){0.f,0.f,0.f,0.f};
#pragma unroll
    for (int nt = 0; nt < 2; ++nt)
#pragma unroll
      for (int kc = 0; kc < 5; ++kc) {
        bf16x8 Bf = *(const bf16x8*)&sH[(nt*16 + r)*PS + kc*32 + g*8];
        acc[nt] = __builtin_amdgcn_mfma_f32_16x16x32_bf16(Af[kc], Bf, acc[nt], 0, 0, 0);
      }
    float b2v[4], w3v[4];
#pragma unroll
    for (int q = 0; q < 4; ++q) {
      int j = jt*16 + g*4 + q;
      b2v[q] = (j < HID) ? ab2[j] : 0.f;
      w3v[q] = (j < HID) ? aw3[j] : 0.f;
    }
#pragma unroll
    for (int nt = 0; nt < 2; ++nt) {
      float p = 0.f;
#pragma unroll
      for (int q = 0; q < 4; ++q)
        p += fmaxf(acc[nt][q] + b2v[q], 0.f) * w3v[q];
      p += __shfl_xor(p, 16);
      p += __shfl_xor(p, 32);
      if (g == 0) red[nt*16 + r][wv] = p;
    }
  }
  __syncthreads();
  if (t < 32) {
    float s = ab3[0];
#pragma unroll
    for (int w = 0; w < 10; ++w) s += red[t][w];
    sATT[t] = s;
  }
  __syncthreads();

  // ---- Phase B: prefix softmax per start
  if (t < SPB) {
    int i1 = i1b + t;
    if (i1 < NSTART) {
      float a[10];
#pragma unroll
      for (int l = 0; l < 10; ++l) a[l] = sATT[t + l];
      float M = a[0];
#pragma unroll
      for (int l = 1; l < 10; ++l) M = fmaxf(M, a[l]);
      float D = 0.f;
#pragma unroll
      for (int l = 0; l < 10; ++l) {
        float e = expf(a[l] - M);
        D += e;
        sE[t][l] = e;
        sI[t][l] = 1.f / D;
      }
    } else {
#pragma unroll
      for (int l = 0; l < 10; ++l) { sE[t][l] = 0.f; sI[t][l] = 0.f; }
    }
  }
  __syncthreads();

  // ---- Phase C: build H1 (bf16) in LDS
  const float* SA = ws + OFF_SA;
  const float* SBp = ws + OFF_SB;
  const float* EC = ws + OFF_EC;
  const float* WT = ws + OFF_WT;
  const int binrow[10] = {1,2,3,4,4,4,4,5,5,5};

#pragma unroll
  for (int rep = 0; rep < 2; ++rep) {
    int u = rep*640 + t;                 // 0..1279
    int sl = u / 160, jj = u - sl*160;
    int i1 = i1b + sl;
    if (jj < HID) {
      float sa = SA[(size_t)i1*RS + jj];
      float rs = 0.f;
#pragma unroll
      for (int l = 0; l < 10; ++l) {
        // i1+l may reach 2048 for the one invalid start; that row aliases the
        // WT region (finite, written) and feeds only discarded spans.
        rs = fmaf(sE[sl][l], EC[(size_t)(i1+l)*RS + jj], rs);
        float h = sa + SBp[(size_t)(i1+l)*RS + jj] + WT[binrow[l]*RS + jj]
                + rs * sI[sl][l];
        sH[(sl*10 + l)*PS + jj] = f2bf(fmaxf(h, 0.f));
      }
    } else {
#pragma unroll
      for (int l = 0; l < 10; ++l) sH[(sl*10 + l)*PS + jj] = 0;
    }
  }
  __syncthreads();

  // ---- Phase D: layer-2 MFMA + fused W3 reduce
  const int jt = wv;
  bf16x8 Af[5];
#pragma unroll
  for (int kc = 0; kc < 5; ++kc)
    Af[kc] = *(const bf16x8*)&W2t[(size_t)(jt*16 + r)*160 + kc*32 + g*8];
  f32x4 acc[5];
#pragma unroll
  for (int nt = 0; nt < 5; ++nt) acc[nt] = (f32x4){0.f,0.f,0.f,0.f};
#pragma unroll
  for (int nt = 0; nt < 5; ++nt)
#pragma unroll
    for (int kc = 0; kc < 5; ++kc) {
      bf16x8 Bf = *(const bf16x8*)&sH[(nt*16 + r)*PS + kc*32 + g*8];
      acc[nt] = __builtin_amdgcn_mfma_f32_16x16x32_bf16(Af[kc], Bf, acc[nt], 0, 0, 0);
    }

  float b2v[4], w3v[4];
#pragma unroll
  for (int q = 0; q < 4; ++q) {
    int j = jt*16 + g*4 + q;
    b2v[q] = (j < HID) ? sb2[j] : 0.f;
    w3v[q] = (j < HID) ? sw3[j] : 0.f;
  }
#pragma unroll
  for (int nt = 0; nt < 5; ++nt) {
    float p = 0.f;
#pragma unroll
    for (int q = 0; q < 4; ++q)
      p += fmaxf(acc[nt][q] + b2v[q], 0.f) * w3v[q];
    p += __shfl_xor(p, 16);
    p += __shfl_xor(p, 32);
    if (g == 0) red[nt*16 + r][wv] = p;
  }
  __syncthreads();
  if (t < 80) {
    int ng = i1b*10 + t;
    if (ng < NSPAN) {
      float s = sb3[0];
#pragma unroll
      for (int w = 0; w < 10; ++w) s += red[t][w];
      out[ng] = s;
    }
  }
}

extern "C" void kernel_launch(void* const* d_in, const int* in_sizes, int n_in,
                              void* d_out, int out_size, void* d_ws, size_t ws_size,
                              hipStream_t stream) {
  const float* states      = (const float*)d_in[0];
  const float* embeds      = (const float*)d_in[1];
  const float* attn_W1     = (const float*)d_in[2];
  const float* attn_b1     = (const float*)d_in[3];
  const float* attn_W2     = (const float*)d_in[4];
  const float* attn_b2     = (const float*)d_in[5];
  const float* attn_W3     = (const float*)d_in[6];
  const float* attn_b3     = (const float*)d_in[7];
  const float* width_table = (const float*)d_in[8];
  const float* score_W1    = (const float*)d_in[9];
  const float* score_b1    = (const float*)d_in[10];
  const float* score_W2    = (const float*)d_in[11];
  const float* score_b2    = (const float*)d_in[12];
  const float* score_W3    = (const float*)d_in[13];
  const float* score_b3    = (const float*)d_in[14];
  float* out = (float*)d_out;
  float* ws  = (float*)d_ws;

  unsigned short* Wt   = (unsigned short*)(ws + OFF_BF16);
  unsigned short* W2t  = Wt + 640*AD;
  unsigned short* AW2t = W2t + 25600;

  k_pack<<<265, 256, 0, stream>>>(attn_W1, score_W1, score_W2, attn_W2,
                                  width_table, score_b1, Wt, W2t, AW2t, ws);
  k_gemm<<<dim3(T_TOK/BM, 8), 320, 0, stream>>>(states, embeds, Wt, attn_b1, ws);
  k_span<<<(NSTART+SPB-1)/SPB, 640, 0, stream>>>(W2t, AW2t,
                                  attn_b2, attn_W3, attn_b3,
                                  score_b2, score_W3, score_b3, ws, out);
}

// Round 6
// 42.980 us; speedup vs baseline: 4.9540x; 1.0026x over previous
//
#include <hip/hip_runtime.h>

#define T_TOK 2048
#define AD    1024
#define HID   150
#define LW    10
#define NSTART (T_TOK - LW + 1)   // 2039
#define NSPAN  (NSTART * LW)      // 20390
#define RS    152                 // padded fp32 row stride

// workspace offsets (in floats)
#define OFF_AH  0
#define OFF_SA  (OFF_AH + T_TOK*RS)
#define OFF_SB  (OFF_SA + T_TOK*RS)
#define OFF_EC  (OFF_SB + T_TOK*RS)
#define OFF_WT  (OFF_EC + T_TOK*RS)     // 16 rows reserved
#define OFF_ATT (OFF_WT + 16*RS)
#define OFF_BF16 (OFF_ATT + T_TOK)

typedef __attribute__((ext_vector_type(8))) short bf16x8;
typedef __attribute__((ext_vector_type(4))) float f32x4;

__device__ inline unsigned short f2bf(float f) {
  unsigned u = __builtin_bit_cast(unsigned, f);
  u += 0x7fff + ((u >> 16) & 1);        // RNE
  return (unsigned short)(u >> 16);
}

__device__ inline unsigned cvt2(float lo, float hi) {   // packed bf16x2, RNE
  unsigned r;
  asm("v_cvt_pk_bf16_f32 %0, %1, %2" : "=v"(r) : "v"(lo), "v"(hi));
  return r;
}

__device__ inline void gld16(const void* g, void* l) {
  __builtin_amdgcn_global_load_lds(
      (const __attribute__((address_space(1))) unsigned int*)g,
      (__attribute__((address_space(3))) unsigned int*)l, 16, 0, 0);
}

// ---------------------------------------------------------------------------
// k_pack: weight packing only (unchanged from R5).
// ---------------------------------------------------------------------------
__global__ __launch_bounds__(256) void k_pack(
    const float* __restrict__ aw1, const float* __restrict__ sw1,
    const float* __restrict__ sw2, const float* __restrict__ aw2,
    const float* __restrict__ width_table, const float* __restrict__ score_b1,
    unsigned short* __restrict__ Wt,
    unsigned short* __restrict__ W2t, unsigned short* __restrict__ AW2t,
    float* __restrict__ ws) {
  __shared__ unsigned short T[152*72];    // 21.9 KB
  const int b = blockIdx.x, t = threadIdx.x;

  if (b < 64) {                         // ---- W1 transpose
    const int grp = b >> 4, kt = b & 15;
    const float* src = (grp == 0) ? aw1 : sw1 + (size_t)(grp-1)*AD*HID;
    const int k0 = kt * 64;
    for (int idx = t; idx < 64*152; idx += 256) {
      int kl = idx / 152, j = idx - kl*152;
      float v = (j < HID) ? src[(size_t)(k0+kl)*HID + j] : 0.f;
      T[j*72 + kl] = f2bf(v);
    }
    __syncthreads();
    for (int u = t; u < 160*8; u += 256) {
      int jj = u >> 3, kc = u & 7;
      bf16x8 v;
      if (jj < 152) v = *(const bf16x8*)&T[jj*72 + kc*8];
      else          v = (bf16x8){0,0,0,0,0,0,0,0};
      *(bf16x8*)&Wt[(size_t)(grp*160 + jj)*AD + k0 + kc*8] = v;
    }
  } else if (b < 264) {                 // ---- W2 packs (both MLPs)
    int idx = (b - 64) * 256 + t;       // 0..51199
    const float* src; unsigned short* dst; int u;
    if (idx < 25600) { src = sw2; dst = W2t; u = idx; }
    else             { src = aw2; dst = AW2t; u = idx - 25600; }
    int j = u / 160, k = u - j*160;
    float v = (j < HID && k < HID) ? src[(size_t)k*HID + j] : 0.f;
    dst[u] = f2bf(v);
  } else {                              // ---- WT width-bucket rows
    const int j = t;
    if (j < HID) {
      float* WT = ws + OFF_WT;
      for (int bb = 0; bb < 9; ++bb) {
        float acc = score_b1[j];
#pragma unroll
        for (int d = 0; d < 20; ++d)
          acc = fmaf(width_table[bb*20 + d], sw1[(size_t)(3*AD + d)*HID + j], acc);
        WT[bb*RS + j] = acc;
      }
    }
  }
}

// ---------------------------------------------------------------------------
// k_gemm: layer-1 bf16 MFMA, fused fp32->bf16 on the A path.
//   Schedule per K-step (T14 issue-early/write-late):
//     loads issued -> MFMA on current buf -> cvt+ds_write (vmcnt overlapped
//     by MFMA phase) -> __syncthreads.
// ---------------------------------------------------------------------------
#define BM 32
#define KS 64
__global__ __launch_bounds__(320) void k_gemm(
    const float* __restrict__ st, const float* __restrict__ em,
    const unsigned short* __restrict__ Wt, const float* __restrict__ attn_b1,
    float* __restrict__ ws) {
  const int m0   = blockIdx.x * BM;
  const int s    = blockIdx.y >> 1;
  const int half = blockIdx.y & 1;
  const int tid  = threadIdx.x;
  const int lane = tid & 63, wv = tid >> 6;

  __shared__ unsigned short lA[2][BM*KS];   // 2 x 4KB
  __shared__ unsigned short lB[2][80*KS];   // 2 x 10KB

  const float* Ag = (s < 3 ? st : em) + (size_t)m0 * AD;
  const unsigned short* Bg = Wt + (size_t)(s*160 + half*80) * AD;

  f32x4 acc0 = {0.f,0.f,0.f,0.f}, acc1 = {0.f,0.f,0.f,0.f};

  const int arow = tid >> 3, ach = tid & 7;           // A chunk = tid (tid<256)
  const float* asrc = Ag + (size_t)arow*AD + ((ach ^ (arow & 7)) << 3);

  auto stageB = [&](int kb, int buf) {
    for (int seg = wv; seg < 10; seg += 5) {
      int c = seg*64 + lane;
      int row = c >> 3, ch = c & 7;
      gld16(Bg + (size_t)row*AD + kb + ((ch ^ (row & 7)) << 3), &lB[buf][seg*512]);
    }
  };

  const int r = lane & 15, g = lane >> 4;
  const int rx = wv*16 + r;
  const int sw = r & 7;

  float4 ra, rc;
  // prologue: tile 0
  if (tid < 256) { ra = *(const float4*)asrc; rc = *(const float4*)(asrc + 4); }
  stageB(0, 0);
  if (tid < 256) {
    uint4 o;
    o.x = cvt2(ra.x, ra.y); o.y = cvt2(ra.z, ra.w);
    o.z = cvt2(rc.x, rc.y); o.w = cvt2(rc.z, rc.w);
    *(uint4*)&lA[0][tid*8] = o;
  }
  __syncthreads();

  for (int kk = 0; kk < 16; ++kk) {
    const int buf = kk & 1;
    if (kk < 15) {
      const int kb = (kk+1)*KS;
      if (tid < 256) { ra = *(const float4*)(asrc + kb); rc = *(const float4*)(asrc + kb + 4); }
      stageB(kb, buf ^ 1);
    }
#pragma unroll
    for (int z = 0; z < 2; ++z) {
      const int cz = z*4 + g;
      bf16x8 X  = *(const bf16x8*)&lB[buf][rx*KS      + ((cz ^ sw) << 3)];
      bf16x8 Y0 = *(const bf16x8*)&lA[buf][r*KS       + ((cz ^ sw) << 3)];
      bf16x8 Y1 = *(const bf16x8*)&lA[buf][(16+r)*KS  + ((cz ^ sw) << 3)];
      acc0 = __builtin_amdgcn_mfma_f32_16x16x32_bf16(X, Y0, acc0, 0, 0, 0);
      acc1 = __builtin_amdgcn_mfma_f32_16x16x32_bf16(X, Y1, acc1, 0, 0, 0);
    }
    if (kk < 15 && tid < 256) {        // write-late: vmcnt wait overlapped by MFMAs
      uint4 o;
      o.x = cvt2(ra.x, ra.y); o.y = cvt2(ra.z, ra.w);
      o.z = cvt2(rc.x, rc.y); o.w = cvt2(rc.z, rc.w);
      *(uint4*)&lA[buf ^ 1][tid*8] = o;
    }
    __syncthreads();
  }

  const int jn = half*80 + wv*16 + g*4;
  float* Cp = ws + (s==0 ? OFF_AH : s==1 ? OFF_SA : s==2 ? OFF_SB : OFF_EC);
#pragma unroll
  for (int f = 0; f < 2; ++f) {
    int m = m0 + f*16 + r;
    f32x4 a = f ? acc1 : acc0;
    if (s == 0) {
#pragma unroll
      for (int q = 0; q < 4; ++q)
        if (jn + q < HID) a[q] = fmaxf(a[q] + attn_b1[jn+q], 0.f);
    }
    float* d = Cp + (size_t)m*RS + jn;
    if (jn + 3 < HID) *(f32x4*)d = a;
    else {
#pragma unroll
      for (int q = 0; q < 4; ++q) if (jn + q < HID) d[q] = a[q];
    }
  }
}

#define PS 168   // bf16 LDS row stride
#define FR 152   // fp32 LDS row stride (floats)

// ---------------------------------------------------------------------------
// k_span: per block of 8 starts (80 spans). All global inputs staged into LDS
// up front with coalesced loads; phases then run out of LDS.
//   A) attn logits for the 17-token window (bf16 MFMA vs AW2t)
//   B) prefix softmax per start
//   C) H1 build (bf16) into LDS, reading staged fSB/fEC/fSA/fWT
//   D) layer-2 MFMA vs W2t + fused relu*W3 reduce -> out
// ---------------------------------------------------------------------------
#define SPB 8
__global__ __launch_bounds__(640) void k_span(
    const unsigned short* __restrict__ W2t,
    const unsigned short* __restrict__ AW2t,
    const float* __restrict__ ab2, const float* __restrict__ aw3,
    const float* __restrict__ ab3,
    const float* __restrict__ sb2, const float* __restrict__ sw3,
    const float* __restrict__ sb3,
    const float* __restrict__ ws, float* __restrict__ out) {
  const int i1b = blockIdx.x * SPB;
  const int t = threadIdx.x, lane = t & 63, wv = t >> 6;
  const int r = lane & 15, g = lane >> 4;
  __shared__ unsigned short sH[80 * PS];            // 26.9 KB
  __shared__ float fSB[17*FR], fEC[17*FR];          // 2 x 10.3 KB
  __shared__ float fSA[8*FR],  fWT[6*FR];           // 4.9 + 3.6 KB
  __shared__ float red[80][10];
  __shared__ float sATT[32];
  __shared__ float sE[SPB][10], sI[SPB][10];
  const float* AH  = ws + OFF_AH;
  const float* SA  = ws + OFF_SA;
  const float* SBp = ws + OFF_SB;
  const float* EC  = ws + OFF_EC;
  const float* WT  = ws + OFF_WT;

  // ---- Stage: AH window -> sH (bf16), SB/EC/SA/WT windows -> fp32 LDS.
  for (int u = t; u < 32*160; u += 640) {
    int row = u / 160, jj = u - row*160;
    int tok = i1b + row;
    float v = (row < 17 && jj < HID && tok < T_TOK) ? AH[(size_t)tok*RS + jj] : 0.f;
    sH[row*PS + jj] = f2bf(v);
  }
  // 48 rows x 38 float4 = 1824 float4 loads, coalesced.
  // Rows i1b+16 may index row 2048: aliases the next ws region (finite,
  // written) and feeds only discarded spans.
  for (int u = t; u < 48*38; u += 640) {
    int row = u / 38, c4 = u - row*38;
    const float* gsrc; float* ldst;
    if (row < 17)      { gsrc = SBp + (size_t)(i1b+row)*RS;    ldst = fSB + row*FR; }
    else if (row < 34) { gsrc = EC  + (size_t)(i1b+row-17)*RS; ldst = fEC + (row-17)*FR; }
    else if (row < 42) { gsrc = SA  + (size_t)(i1b+row-34)*RS; ldst = fSA + (row-34)*FR; }
    else               { gsrc = WT  + (size_t)(row-42)*RS;     ldst = fWT + (row-42)*FR; }
    *(float4*)(ldst + c4*4) = *(const float4*)(gsrc + c4*4);
  }
  __syncthreads();

  // ---- Phase A: attention logits for tokens i1b..i1b+16
  {
    const int jt = wv;
    bf16x8 Af[5];
#pragma unroll
    for (int kc = 0; kc < 5; ++kc)
      Af[kc] = *(const bf16x8*)&AW2t[(size_t)(jt*16 + r)*160 + kc*32 + g*8];
    f32x4 acc[2];
#pragma unroll
    for (int nt = 0; nt < 2; ++nt) acc[nt] = (f32x4){0.f,0.f,0.f,0.f};
#pragma unroll
    for (int nt = 0; nt < 2; ++nt)
#pragma unroll
      for (int kc = 0; kc < 5; ++kc) {
        bf16x8 Bf = *(const bf16x8*)&sH[(nt*16 + r)*PS + kc*32 + g*8];
        acc[nt] = __builtin_amdgcn_mfma_f32_16x16x32_bf16(Af[kc], Bf, acc[nt], 0, 0, 0);
      }
    float b2v[4], w3v[4];
#pragma unroll
    for (int q = 0; q < 4; ++q) {
      int j = jt*16 + g*4 + q;
      b2v[q] = (j < HID) ? ab2[j] : 0.f;
      w3v[q] = (j < HID) ? aw3[j] : 0.f;
    }
#pragma unroll
    for (int nt = 0; nt < 2; ++nt) {
      float p = 0.f;
#pragma unroll
      for (int q = 0; q < 4; ++q)
        p += fmaxf(acc[nt][q] + b2v[q], 0.f) * w3v[q];
      p += __shfl_xor(p, 16);
      p += __shfl_xor(p, 32);
      if (g == 0) red[nt*16 + r][wv] = p;
    }
  }
  __syncthreads();
  if (t < 32) {
    float s = ab3[0];
#pragma unroll
    for (int w = 0; w < 10; ++w) s += red[t][w];
    sATT[t] = s;
  }
  __syncthreads();

  // ---- Phase B: prefix softmax per start
  if (t < SPB) {
    int i1 = i1b + t;
    if (i1 < NSTART) {
      float a[10];
#pragma unroll
      for (int l = 0; l < 10; ++l) a[l] = sATT[t + l];
      float M = a[0];
#pragma unroll
      for (int l = 1; l < 10; ++l) M = fmaxf(M, a[l]);
      float D = 0.f;
#pragma unroll
      for (int l = 0; l < 10; ++l) {
        float e = expf(a[l] - M);
        D += e;
        sE[t][l] = e;
        sI[t][l] = 1.f / D;
      }
    } else {
#pragma unroll
      for (int l = 0; l < 10; ++l) { sE[t][l] = 0.f; sI[t][l] = 0.f; }
    }
  }
  __syncthreads();

  // ---- Phase C: build H1 (bf16) in LDS from staged windows
  const int binrow[10] = {1,2,3,4,4,4,4,5,5,5};
#pragma unroll
  for (int rep = 0; rep < 2; ++rep) {
    int u = rep*640 + t;                 // 0..1279
    int sl = u / 160, jj = u - sl*160;
    if (jj < HID) {
      float sa = fSA[sl*FR + jj];
      float rs = 0.f;
#pragma unroll
      for (int l = 0; l < 10; ++l) {
        rs = fmaf(sE[sl][l], fEC[(sl+l)*FR + jj], rs);
        float h = sa + fSB[(sl+l)*FR + jj] + fWT[binrow[l]*FR + jj]
                + rs * sI[sl][l];
        sH[(sl*10 + l)*PS + jj] = f2bf(fmaxf(h, 0.f));
      }
    } else {
#pragma unroll
      for (int l = 0; l < 10; ++l) sH[(sl*10 + l)*PS + jj] = 0;
    }
  }
  __syncthreads();

  // ---- Phase D: layer-2 MFMA + fused W3 reduce
  const int jt = wv;
  bf16x8 Af[5];
#pragma unroll
  for (int kc = 0; kc < 5; ++kc)
    Af[kc] = *(const bf16x8*)&W2t[(size_t)(jt*16 + r)*160 + kc*32 + g*8];
  f32x4 acc[5];
#pragma unroll
  for (int nt = 0; nt < 5; ++nt) acc[nt] = (f32x4){0.f,0.f,0.f,0.f};
#pragma unroll
  for (int nt = 0; nt < 5; ++nt)
#pragma unroll
    for (int kc = 0; kc < 5; ++kc) {
      bf16x8 Bf = *(const bf16x8*)&sH[(nt*16 + r)*PS + kc*32 + g*8];
      acc[nt] = __builtin_amdgcn_mfma_f32_16x16x32_bf16(Af[kc], Bf, acc[nt], 0, 0, 0);
    }

  float b2v[4], w3v[4];
#pragma unroll
  for (int q = 0; q < 4; ++q) {
    int j = jt*16 + g*4 + q;
    b2v[q] = (j < HID) ? sb2[j] : 0.f;
    w3v[q] = (j < HID) ? sw3[j] : 0.f;
  }
#pragma unroll
  for (int nt = 0; nt < 5; ++nt) {
    float p = 0.f;
#pragma unroll
    for (int q = 0; q < 4; ++q)
      p += fmaxf(acc[nt][q] + b2v[q], 0.f) * w3v[q];
    p += __shfl_xor(p, 16);
    p += __shfl_xor(p, 32);
    if (g == 0) red[nt*16 + r][wv] = p;
  }
  __syncthreads();
  if (t < 80) {
    int ng = i1b*10 + t;
    if (ng < NSPAN) {
      float s = sb3[0];
#pragma unroll
      for (int w = 0; w < 10; ++w) s += red[t][w];
      out[ng] = s;
    }
  }
}

extern "C" void kernel_launch(void* const* d_in, const int* in_sizes, int n_in,
                              void* d_out, int out_size, void* d_ws, size_t ws_size,
                              hipStream_t stream) {
  const float* states      = (const float*)d_in[0];
  const float* embeds      = (const float*)d_in[1];
  const float* attn_W1     = (const float*)d_in[2];
  const float* attn_b1     = (const float*)d_in[3];
  const float* attn_W2     = (const float*)d_in[4];
  const float* attn_b2     = (const float*)d_in[5];
  const float* attn_W3     = (const float*)d_in[6];
  const float* attn_b3     = (const float*)d_in[7];
  const float* width_table = (const float*)d_in[8];
  const float* score_W1    = (const float*)d_in[9];
  const float* score_b1    = (const float*)d_in[10];
  const float* score_W2    = (const float*)d_in[11];
  const float* score_b2    = (const float*)d_in[12];
  const float* score_W3    = (const float*)d_in[13];
  const float* score_b3    = (const float*)d_in[14];
  float* out = (float*)d_out;
  float* ws  = (float*)d_ws;

  unsigned short* Wt   = (unsigned short*)(ws + OFF_BF16);
  unsigned short* W2t  = Wt + 640*AD;
  unsigned short* AW2t = W2t + 25600;

  k_pack<<<265, 256, 0, stream>>>(attn_W1, score_W1, score_W2, attn_W2,
                                  width_table, score_b1, Wt, W2t, AW2t, ws);
  k_gemm<<<dim3(T_TOK/BM, 8), 320, 0, stream>>>(states, embeds, Wt, attn_b1, ws);
  k_span<<<(NSTART+SPB-1)/SPB, 640, 0, stream>>>(W2t, AW2t,
                                  attn_b2, attn_W3, attn_b3,
                                  score_b2, score_W3, score_b3, ws, out);
}